// Round 1
// baseline (213.985 us; speedup 1.0000x reference)
//
#include <hip/hip_runtime.h>
#include <hip/hip_bf16.h>
#include <stdint.h>

#define DEV __device__ __forceinline__

typedef __bf16 bf16x8 __attribute__((ext_vector_type(8)));
typedef float f32x4 __attribute__((ext_vector_type(4)));

DEV uint16_t f2bf(float f) {
  union { float f; uint32_t u; } c; c.f = f;
  uint32_t u = c.u;
  u += 0x7fffu + ((u >> 16) & 1u);   // round-to-nearest-even
  return (uint16_t)(u >> 16);
}

// ---------------- elementwise f32 -> bf16 ----------------
__global__ void cvt_bf16_kernel(const float* __restrict__ in, uint16_t* __restrict__ out, int n4) {
  int i = blockIdx.x * blockDim.x + threadIdx.x;
  if (i >= n4) return;
  float4 v = reinterpret_cast<const float4*>(in)[i];
  ushort4 o;
  o.x = f2bf(v.x); o.y = f2bf(v.y); o.z = f2bf(v.z); o.w = f2bf(v.w);
  reinterpret_cast<ushort4*>(out)[i] = o;
}

// ---------------- transpose f32 [R,C] -> bf16 [C,R] ----------------
__global__ void transpose_cvt_kernel(const float* __restrict__ in, uint16_t* __restrict__ out,
                                     int R, int C) {
  __shared__ float t[32][33];
  const int tx = threadIdx.x, ty = threadIdx.y;          // blockDim (32,8)
  const int c0 = blockIdx.x * 32, r0 = blockIdx.y * 32;
#pragma unroll
  for (int i = 0; i < 4; ++i)
    t[ty + i * 8][tx] = in[(size_t)(r0 + ty + i * 8) * C + (c0 + tx)];
  __syncthreads();
#pragma unroll
  for (int i = 0; i < 4; ++i)
    out[(size_t)(c0 + ty + i * 8) * R + (r0 + tx)] = f2bf(t[tx][ty + i * 8]);
}

// ---------------- GEMM: C = A[M,K] * Bt[N,K]^T, bf16 in, f32 acc ----------------
// MODE 0: out = bf16(acc + bias)
// MODE 1: out = f32(acc + bias + res)
// MODE 2: out = bf16(relu(acc + bias))
constexpr int BM = 128, BN = 128, BK = 32;

template <int MODE>
__launch_bounds__(256, 2)
__global__ void gemm_bt_kernel(const uint16_t* __restrict__ A,
                               const uint16_t* __restrict__ Bt,
                               const float* __restrict__ bias,
                               const float* __restrict__ res,
                               void* __restrict__ out,
                               int M, int N, int K) {
  __shared__ uint16_t sA[BM * BK];   // 8 KB
  __shared__ uint16_t sB[BN * BK];   // 8 KB
  const int tid  = threadIdx.x;
  const int lane = tid & 63;
  const int wave = tid >> 6;
  const int m0 = blockIdx.y * BM;
  const int n0 = blockIdx.x * BN;
  const int wm = (wave >> 1) * 64;
  const int wn = (wave & 1) * 64;

  f32x4 acc[4][4] = {};

  // staging: tile is 512 chunks of 16B; thread handles chunks {tid, tid+256}
  const int row = tid >> 2;          // 0..63
  const int cc  = (tid & 3) * 8;     // element offset within the BK=32 row

  const uint16_t* gA0 = A  + (size_t)(m0 + row) * K + cc;
  const uint16_t* gA1 = A  + (size_t)(m0 + row + 64) * K + cc;
  const uint16_t* gB0 = Bt + (size_t)(n0 + row) * K + cc;
  const uint16_t* gB1 = Bt + (size_t)(n0 + row + 64) * K + cc;
  uint16_t* lA0 = sA + tid * 8;
  uint16_t* lA1 = sA + (tid + 256) * 8;
  uint16_t* lB0 = sB + tid * 8;
  uint16_t* lB1 = sB + (tid + 256) * 8;

  const int fr   = lane & 15;
  const int krow = (lane >> 4) * 8;

  const int nk = K / BK;
  for (int kt = 0; kt < nk; ++kt) {
    __syncthreads();
    __builtin_amdgcn_global_load_lds((const __attribute__((address_space(1))) uint32_t*)gA0,
                                     (__attribute__((address_space(3))) uint32_t*)lA0, 16, 0, 0);
    __builtin_amdgcn_global_load_lds((const __attribute__((address_space(1))) uint32_t*)gA1,
                                     (__attribute__((address_space(3))) uint32_t*)lA1, 16, 0, 0);
    __builtin_amdgcn_global_load_lds((const __attribute__((address_space(1))) uint32_t*)gB0,
                                     (__attribute__((address_space(3))) uint32_t*)lB0, 16, 0, 0);
    __builtin_amdgcn_global_load_lds((const __attribute__((address_space(1))) uint32_t*)gB1,
                                     (__attribute__((address_space(3))) uint32_t*)lB1, 16, 0, 0);
    gA0 += BK; gA1 += BK; gB0 += BK; gB1 += BK;
    __syncthreads();

    bf16x8 af[4], bfr[4];
#pragma unroll
    for (int m = 0; m < 4; ++m)
      af[m] = *reinterpret_cast<const bf16x8*>(sA + (wm + m * 16 + fr) * BK + krow);
#pragma unroll
    for (int n = 0; n < 4; ++n)
      bfr[n] = *reinterpret_cast<const bf16x8*>(sB + (wn + n * 16 + fr) * BK + krow);
#pragma unroll
    for (int m = 0; m < 4; ++m)
#pragma unroll
      for (int n = 0; n < 4; ++n)
        acc[m][n] = __builtin_amdgcn_mfma_f32_16x16x32_bf16(af[m], bfr[n], acc[m][n], 0, 0, 0);
  }

  // epilogue: C/D layout col = lane&15, row = (lane>>4)*4 + reg
  const int cn  = lane & 15;
  const int cm4 = (lane >> 4) * 4;
#pragma unroll
  for (int m = 0; m < 4; ++m) {
#pragma unroll
    for (int n = 0; n < 4; ++n) {
      const int gm = m0 + wm + m * 16 + cm4;
      const int gn = n0 + wn + n * 16 + cn;
      const float bb = bias[gn];
#pragma unroll
      for (int r = 0; r < 4; ++r) {
        const size_t idx = (size_t)(gm + r) * N + gn;
        const float vv = acc[m][n][r] + bb;
        if constexpr (MODE == 0) {
          ((uint16_t*)out)[idx] = f2bf(vv);
        } else if constexpr (MODE == 1) {
          ((float*)out)[idx] = vv + res[idx];
        } else {
          ((uint16_t*)out)[idx] = f2bf(fmaxf(vv, 0.f));
        }
      }
    }
  }
}

// ---------------- LayerNorm over rows of 1024 f32 ----------------
__global__ void ln_kernel(const float* __restrict__ in,
                          const float* __restrict__ g,
                          const float* __restrict__ b,
                          float* __restrict__ outf,
                          uint16_t* __restrict__ outb) {
  const int row = blockIdx.x;
  const int t = threadIdx.x;   // 256 threads, 4 floats each
  const float4 v = reinterpret_cast<const float4*>(in + (size_t)row * 1024)[t];
  float s  = v.x + v.y + v.z + v.w;
  float s2 = v.x * v.x + v.y * v.y + v.z * v.z + v.w * v.w;
#pragma unroll
  for (int o = 32; o > 0; o >>= 1) {
    s  += __shfl_down(s, o);
    s2 += __shfl_down(s2, o);
  }
  __shared__ float red[8];
  const int lane = t & 63, wave = t >> 6;
  if (lane == 0) { red[wave] = s; red[4 + wave] = s2; }
  __syncthreads();
  const float S  = red[0] + red[1] + red[2] + red[3];
  const float S2 = red[4] + red[5] + red[6] + red[7];
  const float mu  = S * (1.f / 1024.f);
  const float var = S2 * (1.f / 1024.f) - mu * mu;
  const float rs  = rsqrtf(var + 1e-5f);
  const float4 gg = reinterpret_cast<const float4*>(g)[t];
  const float4 bb = reinterpret_cast<const float4*>(b)[t];
  float4 o;
  o.x = (v.x - mu) * rs * gg.x + bb.x;
  o.y = (v.y - mu) * rs * gg.y + bb.y;
  o.z = (v.z - mu) * rs * gg.z + bb.z;
  o.w = (v.w - mu) * rs * gg.w + bb.w;
  if (outf) reinterpret_cast<float4*>(outf + (size_t)row * 1024)[t] = o;
  if (outb) {
    ushort4 ob;
    ob.x = f2bf(o.x); ob.y = f2bf(o.y); ob.z = f2bf(o.z); ob.w = f2bf(o.w);
    reinterpret_cast<ushort4*>(outb + (size_t)row * 1024)[t] = ob;
  }
}

// ---------------- launch ----------------
extern "C" void kernel_launch(void* const* d_in, const int* in_sizes, int n_in,
                              void* d_out, int out_size, void* d_ws, size_t ws_size,
                              hipStream_t stream) {
  // inputs: 0:x 1:mask 2:Wq 3:bq 4:Wk 5:bk 6:Wv 7:bv 8:Wo 9:bo 10:W1 11:b1 12:W2 13:b2
  //         14:g1 15:beta1 16:g2 17:beta2   (q/k path + mask are dead: hollow attention == identity)
  const float* x   = (const float*)d_in[0];
  const float* Wv  = (const float*)d_in[6];
  const float* bv  = (const float*)d_in[7];
  const float* Wo  = (const float*)d_in[8];
  const float* bo  = (const float*)d_in[9];
  const float* W1  = (const float*)d_in[10];
  const float* b1  = (const float*)d_in[11];
  const float* W2  = (const float*)d_in[12];
  const float* b2  = (const float*)d_in[13];
  const float* g1  = (const float*)d_in[14];
  const float* be1 = (const float*)d_in[15];
  const float* g2  = (const float*)d_in[16];
  const float* be2 = (const float*)d_in[17];
  float* out = (float*)d_out;

  constexpr int M = 4096, DM = 1024, FF = 4096;

  char* p = (char*)d_ws;
  auto alloc = [&](size_t bytes) {
    char* r = p;
    p += (bytes + 255) & ~(size_t)255;
    return r;
  };
  uint16_t* xb  = (uint16_t*)alloc((size_t)M * DM * 2);
  uint16_t* wvt = (uint16_t*)alloc((size_t)DM * DM * 2);
  uint16_t* wot = (uint16_t*)alloc((size_t)DM * DM * 2);
  uint16_t* w1t = (uint16_t*)alloc((size_t)FF * DM * 2);
  uint16_t* w2t = (uint16_t*)alloc((size_t)DM * FF * 2);
  uint16_t* vb  = (uint16_t*)alloc((size_t)M * DM * 2);   // reused as hb after GEMM2
  float*    r1  = (float*)   alloc((size_t)M * DM * 4);   // reused as r2 after LN1
  float*    hf  = (float*)   alloc((size_t)M * DM * 4);
  uint16_t* tb  = (uint16_t*)alloc((size_t)M * FF * 2);
  uint16_t* hb  = vb;   // vb dead after GEMM2
  float*    r2  = r1;   // r1 dead after LN1

  const dim3 tb32(32, 8);

  // precision conversion + weight transposes (so every GEMM is A[M,K] * Bt[N,K])
  cvt_bf16_kernel<<<(M * DM / 4 + 255) / 256, 256, 0, stream>>>(x, xb, M * DM / 4);
  transpose_cvt_kernel<<<dim3(DM / 32, DM / 32), tb32, 0, stream>>>(Wv, wvt, DM, DM);
  transpose_cvt_kernel<<<dim3(DM / 32, DM / 32), tb32, 0, stream>>>(Wo, wot, DM, DM);
  transpose_cvt_kernel<<<dim3(FF / 32, DM / 32), tb32, 0, stream>>>(W1, w1t, DM, FF);
  transpose_cvt_kernel<<<dim3(DM / 32, FF / 32), tb32, 0, stream>>>(W2, w2t, FF, DM);

  // v = x @ Wv + bv              -> bf16
  gemm_bt_kernel<0><<<dim3(DM / BN, M / BM), 256, 0, stream>>>(xb, wvt, bv, nullptr, vb, M, DM, DM);
  // r1 = x + (v @ Wo + bo)       -> f32
  gemm_bt_kernel<1><<<dim3(DM / BN, M / BM), 256, 0, stream>>>(vb, wot, bo, x, r1, M, DM, DM);
  // h = LN(r1)*g1+beta1          -> f32 + bf16
  ln_kernel<<<M, 256, 0, stream>>>(r1, g1, be1, hf, hb);
  // t = relu(h @ W1 + b1)        -> bf16
  gemm_bt_kernel<2><<<dim3(FF / BN, M / BM), 256, 0, stream>>>(hb, w1t, b1, nullptr, tb, M, FF, DM);
  // r2 = h + (t @ W2 + b2)       -> f32
  gemm_bt_kernel<1><<<dim3(DM / BN, M / BM), 256, 0, stream>>>(tb, w2t, b2, hf, r2, M, DM, FF);
  // out = LN(r2)*g2+beta2        -> f32
  ln_kernel<<<M, 256, 0, stream>>>(r2, g2, be2, out, nullptr);
}

// Round 2
// 162.828 us; speedup vs baseline: 1.3142x; 1.3142x over previous
//
#include <hip/hip_runtime.h>
#include <stdint.h>

typedef __bf16 bf16x8 __attribute__((ext_vector_type(8)));
typedef float f32x4 __attribute__((ext_vector_type(4)));

__device__ __forceinline__ uint16_t f2bf(float f) {
  union { float f; uint32_t u; } c; c.f = f;
  uint32_t u = c.u;
  u += 0x7fffu + ((u >> 16) & 1u);   // round-to-nearest-even
  return (uint16_t)(u >> 16);
}
__device__ __forceinline__ float bf2f(uint16_t u) {
  union { uint32_t u; float f; } c; c.u = (uint32_t)u << 16; return c.f;
}

// ---------------- elementwise f32 -> bf16 ----------------
__global__ void cvt_bf16_kernel(const float* __restrict__ in, uint16_t* __restrict__ out, int n4) {
  int i = blockIdx.x * blockDim.x + threadIdx.x;
  if (i >= n4) return;
  float4 v = reinterpret_cast<const float4*>(in)[i];
  ushort4 o;
  o.x = f2bf(v.x); o.y = f2bf(v.y); o.z = f2bf(v.z); o.w = f2bf(v.w);
  reinterpret_cast<ushort4*>(out)[i] = o;
}

// ---------------- transpose f32 [R,C] -> bf16 [C,R] ----------------
__global__ void transpose_cvt_kernel(const float* __restrict__ in, uint16_t* __restrict__ out,
                                     int R, int C) {
  __shared__ float t[32][33];
  const int tx = threadIdx.x, ty = threadIdx.y;          // blockDim (32,8)
  const int c0 = blockIdx.x * 32, r0 = blockIdx.y * 32;
#pragma unroll
  for (int i = 0; i < 4; ++i)
    t[ty + i * 8][tx] = in[(size_t)(r0 + ty + i * 8) * C + (c0 + tx)];
  __syncthreads();
#pragma unroll
  for (int i = 0; i < 4; ++i)
    out[(size_t)(c0 + ty + i * 8) * R + (r0 + tx)] = f2bf(t[tx][ty + i * 8]);
}

// ---------------- bc = bv @ Wo + bo  (f32, exact) ----------------
__global__ void bc_kernel(const float* __restrict__ bv, const float* __restrict__ Wo,
                          const float* __restrict__ bo, float* __restrict__ bc) {
  // grid 32 x 256 threads; block handles 32 output cols
  const int jl = threadIdx.x & 31, kg = threadIdx.x >> 5;   // kg in 0..7
  const int j = blockIdx.x * 32 + jl;
  float s = 0.f;
  const int k0 = kg * 128;
  for (int k = k0; k < k0 + 128; ++k)
    s += bv[k] * Wo[(size_t)k * 1024 + j];
  __shared__ float red[8][32];
  red[kg][jl] = s;
  __syncthreads();
  if (kg == 0) {
    float t = bo[j];
#pragma unroll
    for (int q = 0; q < 8; ++q) t += red[q][jl];
    bc[j] = t;
  }
}

// ---------------- 2-phase double-buffered GEMM ----------------
// C[M,N] = A[M,K(lda)] * Bt[N,K(ldb)]^T ; bf16 in, f32 acc
// MODE 0: bf16(acc + bias?)        MODE 1: f32(acc + bias + res)
// MODE 2: bf16(relu(acc + bias))   MODE 3: f32(acc), out += z*M*N (split-K partial)
constexpr int BM = 128, BN = 128, BK = 64;

template <int MODE>
__launch_bounds__(256, 2)
__global__ void gemm2ph_kernel(const uint16_t* __restrict__ A, const uint16_t* __restrict__ Bt,
                               const float* __restrict__ bias, const float* __restrict__ res,
                               void* __restrict__ out, int M, int N, int Klen, int lda, int ldb) {
  __shared__ uint16_t sAB[2][2][BM * BK];   // [buf][A|B][128*64] = 64 KB
  const int tid  = threadIdx.x;
  const int lane = tid & 63;
  const int wave = tid >> 6;

  // bijective XCD swizzle (all grids have nwg % 8 == 0)
  const int nwg = gridDim.x * gridDim.y;
  int wg = blockIdx.y * gridDim.x + blockIdx.x;
  wg = (wg & 7) * (nwg >> 3) + (wg >> 3);
  const int bx = wg % gridDim.x, by = wg / gridDim.x;
  const int m0 = by * BM, n0 = bx * BN;

  const int z = blockIdx.z;           // split-K chunk (0 unless MODE 3)
  A  += (size_t)z * Klen;
  Bt += (size_t)z * Klen;

  const int wm = (wave >> 1) * 64;
  const int wn = (wave & 1) * 64;

  f32x4 acc[4][4] = {};

  // staging: 1024 chunks of 16B per tile; thread t handles chunks {t, t+256, t+512, t+768}
  // LDS is written linearly; global SOURCE column is inverse-swizzled (rule 21)
  const int srow = tid >> 3;                               // 0..31
  const int scol = ((tid & 7) ^ (srow & 7)) * 8;           // swizzled slot -> elem offset
  const uint16_t* ga[4];
  const uint16_t* gb[4];
  uint32_t loff[4];
#pragma unroll
  for (int g = 0; g < 4; ++g) {
    const int row = srow + 32 * g;
    ga[g] = A + (size_t)(m0 + row) * lda + scol;
    gb[g] = Bt + (size_t)(n0 + row) * ldb + scol;
    loff[g] = (uint32_t)(tid + g * 256) * 8;
  }

  const int fr = lane & 15;
  const int hi = lane >> 4;            // 0..3
  const int rx = fr & 7;

  const int nk = Klen / BK;

#define STAGE(buf, kt)                                                                    \
  {                                                                                       \
    _Pragma("unroll")                                                                     \
    for (int g = 0; g < 4; ++g) {                                                         \
      __builtin_amdgcn_global_load_lds(                                                   \
          (const __attribute__((address_space(1))) uint32_t*)(ga[g] + (size_t)(kt) * BK), \
          (__attribute__((address_space(3))) uint32_t*)(&sAB[buf][0][loff[g]]), 16, 0, 0);\
      __builtin_amdgcn_global_load_lds(                                                   \
          (const __attribute__((address_space(1))) uint32_t*)(gb[g] + (size_t)(kt) * BK), \
          (__attribute__((address_space(3))) uint32_t*)(&sAB[buf][1][loff[g]]), 16, 0, 0);\
    }                                                                                     \
  }

  STAGE(0, 0);
  __syncthreads();                     // drains vmcnt(0): tile 0 resident

  int cur = 0;
  for (int kt = 0; kt < nk; ++kt) {
    if (kt + 1 < nk) STAGE(cur ^ 1, kt + 1);     // prefetch next tile; completes during MFMA
    const uint16_t* pA = &sAB[cur][0][0];
    const uint16_t* pB = &sAB[cur][1][0];
    bf16x8 af[4][2], bb[4][2];
#pragma unroll
    for (int m = 0; m < 4; ++m)
#pragma unroll
      for (int ks = 0; ks < 2; ++ks) {
        const int slot = (ks * 4 + hi) ^ rx;     // swizzled 16B-slot
        af[m][ks] = *reinterpret_cast<const bf16x8*>(pA + (wm + m * 16 + fr) * BK + slot * 8);
        bb[m][ks] = *reinterpret_cast<const bf16x8*>(pB + (wn + m * 16 + fr) * BK + slot * 8);
      }
#pragma unroll
    for (int ks = 0; ks < 2; ++ks)
#pragma unroll
      for (int m = 0; m < 4; ++m)
#pragma unroll
        for (int n = 0; n < 4; ++n)
          acc[m][n] = __builtin_amdgcn_mfma_f32_16x16x32_bf16(af[m][ks], bb[n][ks], acc[m][n], 0, 0, 0);
    __syncthreads();                   // drains prefetch loads + protects buffer reuse
    cur ^= 1;
  }
#undef STAGE

  // epilogue: C/D layout col = lane&15, row = (lane>>4)*4 + reg
  const int cn  = lane & 15;
  const int cm4 = (lane >> 4) * 4;
  float* outf = (MODE == 3) ? ((float*)out + (size_t)z * M * N) : (float*)out;
#pragma unroll
  for (int m = 0; m < 4; ++m) {
#pragma unroll
    for (int n = 0; n < 4; ++n) {
      const int gm = m0 + wm + m * 16 + cm4;
      const int gn = n0 + wn + n * 16 + cn;
      const float bbv = (MODE == 3) ? 0.f : (bias ? bias[gn] : 0.f);
#pragma unroll
      for (int r = 0; r < 4; ++r) {
        const size_t idx = (size_t)(gm + r) * N + gn;
        const float vv = acc[m][n][r] + bbv;
        if constexpr (MODE == 0) {
          ((uint16_t*)out)[idx] = f2bf(vv);
        } else if constexpr (MODE == 1) {
          ((float*)out)[idx] = vv + res[idx];
        } else if constexpr (MODE == 2) {
          ((uint16_t*)out)[idx] = f2bf(fmaxf(vv, 0.f));
        } else {
          outf[idx] = vv;
        }
      }
    }
  }
}

// ---------------- LN1: hb = bf16(LN(r1)*g + b) ----------------
__global__ void ln1_kernel(const float* __restrict__ in,
                           const float* __restrict__ g,
                           const float* __restrict__ b,
                           uint16_t* __restrict__ outb) {
  const int row = blockIdx.x;
  const int t = threadIdx.x;
  const float4 v = reinterpret_cast<const float4*>(in + (size_t)row * 1024)[t];
  float s  = v.x + v.y + v.z + v.w;
  float s2 = v.x * v.x + v.y * v.y + v.z * v.z + v.w * v.w;
#pragma unroll
  for (int o = 32; o > 0; o >>= 1) { s += __shfl_down(s, o); s2 += __shfl_down(s2, o); }
  __shared__ float red[8];
  const int lane = t & 63, wave = t >> 6;
  if (lane == 0) { red[wave] = s; red[4 + wave] = s2; }
  __syncthreads();
  const float S  = red[0] + red[1] + red[2] + red[3];
  const float S2 = red[4] + red[5] + red[6] + red[7];
  const float mu  = S * (1.f / 1024.f);
  const float var = S2 * (1.f / 1024.f) - mu * mu;
  const float rs  = rsqrtf(var + 1e-5f);
  const float4 gg = reinterpret_cast<const float4*>(g)[t];
  const float4 bb = reinterpret_cast<const float4*>(b)[t];
  ushort4 ob;
  ob.x = f2bf((v.x - mu) * rs * gg.x + bb.x);
  ob.y = f2bf((v.y - mu) * rs * gg.y + bb.y);
  ob.z = f2bf((v.z - mu) * rs * gg.z + bb.z);
  ob.w = f2bf((v.w - mu) * rs * gg.w + bb.w);
  reinterpret_cast<ushort4*>(outb + (size_t)row * 1024)[t] = ob;
}

// ---------------- LN2: out = LN(p0+p1+b2+h)*g + be ----------------
__global__ void ln2_kernel(const float* __restrict__ p0, const float* __restrict__ p1,
                           const uint16_t* __restrict__ hb, const float* __restrict__ b2,
                           const float* __restrict__ g, const float* __restrict__ be,
                           float* __restrict__ out) {
  const int row = blockIdx.x;
  const int t = threadIdx.x;
  const size_t base = (size_t)row * 1024;
  const float4 a = reinterpret_cast<const float4*>(p0 + base)[t];
  const float4 b = reinterpret_cast<const float4*>(p1 + base)[t];
  const ushort4 h4 = reinterpret_cast<const ushort4*>(hb + base)[t];
  const float4 c2 = reinterpret_cast<const float4*>(b2)[t];
  float4 v;
  v.x = a.x + b.x + c2.x + bf2f(h4.x);
  v.y = a.y + b.y + c2.y + bf2f(h4.y);
  v.z = a.z + b.z + c2.z + bf2f(h4.z);
  v.w = a.w + b.w + c2.w + bf2f(h4.w);
  float s  = v.x + v.y + v.z + v.w;
  float s2 = v.x * v.x + v.y * v.y + v.z * v.z + v.w * v.w;
#pragma unroll
  for (int o = 32; o > 0; o >>= 1) { s += __shfl_down(s, o); s2 += __shfl_down(s2, o); }
  __shared__ float red[8];
  const int lane = t & 63, wave = t >> 6;
  if (lane == 0) { red[wave] = s; red[4 + wave] = s2; }
  __syncthreads();
  const float S  = red[0] + red[1] + red[2] + red[3];
  const float S2 = red[4] + red[5] + red[6] + red[7];
  const float mu  = S * (1.f / 1024.f);
  const float var = S2 * (1.f / 1024.f) - mu * mu;
  const float rs  = rsqrtf(var + 1e-5f);
  const float4 gg = reinterpret_cast<const float4*>(g)[t];
  const float4 bb = reinterpret_cast<const float4*>(be)[t];
  float4 o;
  o.x = (v.x - mu) * rs * gg.x + bb.x;
  o.y = (v.y - mu) * rs * gg.y + bb.y;
  o.z = (v.z - mu) * rs * gg.z + bb.z;
  o.w = (v.w - mu) * rs * gg.w + bb.w;
  reinterpret_cast<float4*>(out + base)[t] = o;
}

// ---------------- launch ----------------
extern "C" void kernel_launch(void* const* d_in, const int* in_sizes, int n_in,
                              void* d_out, int out_size, void* d_ws, size_t ws_size,
                              hipStream_t stream) {
  // hollow attention == identity: out = attn@v = v, so the layer is
  // r1 = x + x@(Wv@Wo) + (bv@Wo+bo); h = LN1(r1); r2 = h + relu(h@W1+b1)@W2 + b2; out = LN2(r2)
  const float* x   = (const float*)d_in[0];
  const float* Wv  = (const float*)d_in[6];
  const float* bv  = (const float*)d_in[7];
  const float* Wo  = (const float*)d_in[8];
  const float* bo  = (const float*)d_in[9];
  const float* W1  = (const float*)d_in[10];
  const float* b1  = (const float*)d_in[11];
  const float* W2  = (const float*)d_in[12];
  const float* b2  = (const float*)d_in[13];
  const float* g1  = (const float*)d_in[14];
  const float* be1 = (const float*)d_in[15];
  const float* g2  = (const float*)d_in[16];
  const float* be2 = (const float*)d_in[17];
  float* out = (float*)d_out;

  constexpr int M = 4096, DM = 1024, FF = 4096;

  char* p = (char*)d_ws;
  auto alloc = [&](size_t bytes) {
    char* r = p;
    p += (bytes + 255) & ~(size_t)255;
    return r;
  };
  uint16_t* xb  = (uint16_t*)alloc((size_t)M * DM * 2);    // x bf16
  uint16_t* wvb = (uint16_t*)alloc((size_t)DM * DM * 2);   // Wv bf16
  uint16_t* woT = (uint16_t*)alloc((size_t)DM * DM * 2);   // Wo^T bf16
  uint16_t* w1t = (uint16_t*)alloc((size_t)FF * DM * 2);   // W1^T bf16
  uint16_t* w2t = (uint16_t*)alloc((size_t)DM * FF * 2);   // W2^T bf16
  uint16_t* wcT = (uint16_t*)alloc((size_t)DM * DM * 2);   // (Wv@Wo)^T bf16
  float*    bc  = (float*)   alloc((size_t)DM * 4);        // bv@Wo+bo
  float*    r1  = (float*)   alloc((size_t)M * DM * 4);
  uint16_t* hb  = (uint16_t*)alloc((size_t)M * DM * 2);
  uint16_t* tb  = (uint16_t*)alloc((size_t)M * FF * 2);
  float*    pp  = (float*)   alloc((size_t)2 * M * DM * 4);  // split-K partials

  const dim3 tb32(32, 8);

  // precision conversion + weight transposes
  cvt_bf16_kernel<<<M * DM / 4 / 256, 256, 0, stream>>>(x, xb, M * DM / 4);
  cvt_bf16_kernel<<<DM * DM / 4 / 256, 256, 0, stream>>>(Wv, wvb, DM * DM / 4);
  transpose_cvt_kernel<<<dim3(DM / 32, DM / 32), tb32, 0, stream>>>(Wo, woT, DM, DM);
  transpose_cvt_kernel<<<dim3(FF / 32, DM / 32), tb32, 0, stream>>>(W1, w1t, DM, FF);
  transpose_cvt_kernel<<<dim3(DM / 32, FF / 32), tb32, 0, stream>>>(W2, w2t, FF, DM);
  bc_kernel<<<32, 256, 0, stream>>>(bv, Wo, bo, bc);

  // WcT = (Wv@Wo)^T : C[j][i] = sum_k WoT[j][k] * Wv[i][k]
  gemm2ph_kernel<0><<<dim3(DM / BN, DM / BM), 256, 0, stream>>>(
      woT, wvb, nullptr, nullptr, wcT, DM, DM, DM, DM, DM);
  // r1 = x + x@Wc + bc
  gemm2ph_kernel<1><<<dim3(DM / BN, M / BM), 256, 0, stream>>>(
      xb, wcT, bc, x, r1, M, DM, DM, DM, DM);
  // h = LN1(r1)
  ln1_kernel<<<M, 256, 0, stream>>>(r1, g1, be1, hb);
  // t = relu(h@W1 + b1)
  gemm2ph_kernel<2><<<dim3(FF / BN, M / BM), 256, 0, stream>>>(
      hb, w1t, b1, nullptr, tb, M, FF, DM, DM, DM);
  // pp[z] = t[:, z*2048:(z+1)*2048] @ W2[z*2048:(z+1)*2048, :]   (split-K=2)
  gemm2ph_kernel<3><<<dim3(DM / BN, M / BM, 2), 256, 0, stream>>>(
      tb, w2t, nullptr, nullptr, pp, M, DM, FF / 2, FF, FF);
  // out = LN2(h + pp0 + pp1 + b2)
  ln2_kernel<<<M, 256, 0, stream>>>(pp, pp + (size_t)M * DM, hb, b2, g2, be2, out);
}

// Round 3
// 162.023 us; speedup vs baseline: 1.3207x; 1.0050x over previous
//
#include <hip/hip_runtime.h>
#include <stdint.h>

typedef __bf16 bf16x8 __attribute__((ext_vector_type(8)));
typedef float f32x4 __attribute__((ext_vector_type(4)));

__device__ __forceinline__ uint16_t f2bf(float f) {
  union { float f; uint32_t u; } c; c.f = f;
  uint32_t u = c.u;
  u += 0x7fffu + ((u >> 16) & 1u);   // round-to-nearest-even
  return (uint16_t)(u >> 16);
}
__device__ __forceinline__ float bf2f(uint16_t u) {
  union { uint32_t u; float f; } c; c.u = (uint32_t)u << 16; return c.f;
}

// ---------------- elementwise f32 -> bf16 ----------------
__global__ void cvt_bf16_kernel(const float* __restrict__ in, uint16_t* __restrict__ out, int n4) {
  int i = blockIdx.x * blockDim.x + threadIdx.x;
  if (i >= n4) return;
  float4 v = reinterpret_cast<const float4*>(in)[i];
  ushort4 o;
  o.x = f2bf(v.x); o.y = f2bf(v.y); o.z = f2bf(v.z); o.w = f2bf(v.w);
  reinterpret_cast<ushort4*>(out)[i] = o;
}

// ---------------- transpose f32 [R,C] -> bf16 [C,R] ----------------
__global__ void transpose_cvt_kernel(const float* __restrict__ in, uint16_t* __restrict__ out,
                                     int R, int C) {
  __shared__ float t[32][33];
  const int tx = threadIdx.x, ty = threadIdx.y;          // blockDim (32,8)
  const int c0 = blockIdx.x * 32, r0 = blockIdx.y * 32;
#pragma unroll
  for (int i = 0; i < 4; ++i)
    t[ty + i * 8][tx] = in[(size_t)(r0 + ty + i * 8) * C + (c0 + tx)];
  __syncthreads();
#pragma unroll
  for (int i = 0; i < 4; ++i)
    out[(size_t)(c0 + ty + i * 8) * R + (r0 + tx)] = f2bf(t[tx][ty + i * 8]);
}

// ---------------- bc = bv @ Wo + bo  (f32, exact) ----------------
__global__ void bc_kernel(const float* __restrict__ bv, const float* __restrict__ Wo,
                          const float* __restrict__ bo, float* __restrict__ bc) {
  const int jl = threadIdx.x & 31, kg = threadIdx.x >> 5;
  const int j = blockIdx.x * 32 + jl;
  float s = 0.f;
  const int k0 = kg * 128;
  for (int k = k0; k < k0 + 128; ++k)
    s += bv[k] * Wo[(size_t)k * 1024 + j];
  __shared__ float red[8][32];
  red[kg][jl] = s;
  __syncthreads();
  if (kg == 0) {
    float t = bo[j];
#pragma unroll
    for (int q = 0; q < 8; ++q) t += red[q][jl];
    bc[j] = t;
  }
}

// ---------------- 2-phase 128x128 GEMM (small GEMMs) ----------------
// MODE 0: bf16(acc + bias?)   MODE 1: f32(acc + bias + res)
constexpr int BM = 128, BN = 128, BK = 64;

template <int MODE>
__launch_bounds__(256, 2)
__global__ void gemm2ph_kernel(const uint16_t* __restrict__ A, const uint16_t* __restrict__ Bt,
                               const float* __restrict__ bias, const float* __restrict__ res,
                               void* __restrict__ out, int M, int N, int Klen, int lda, int ldb) {
  __shared__ uint16_t sAB[2][2][BM * BK];
  const int tid  = threadIdx.x;
  const int lane = tid & 63;
  const int wave = tid >> 6;

  const int nwg = gridDim.x * gridDim.y;
  int wg = blockIdx.y * gridDim.x + blockIdx.x;
  wg = (wg & 7) * (nwg >> 3) + (wg >> 3);
  const int bx = wg % gridDim.x, by = wg / gridDim.x;
  const int m0 = by * BM, n0 = bx * BN;

  const int wm = (wave >> 1) * 64;
  const int wn = (wave & 1) * 64;

  f32x4 acc[4][4] = {};

  const int srow = tid >> 3;
  const int scol = ((tid & 7) ^ (srow & 7)) * 8;
  const uint16_t* ga[4];
  const uint16_t* gb[4];
  uint32_t loff[4];
#pragma unroll
  for (int g = 0; g < 4; ++g) {
    const int row = srow + 32 * g;
    ga[g] = A + (size_t)(m0 + row) * lda + scol;
    gb[g] = Bt + (size_t)(n0 + row) * ldb + scol;
    loff[g] = (uint32_t)(tid + g * 256) * 8;
  }

  const int fr = lane & 15;
  const int hi = lane >> 4;
  const int rx = fr & 7;

  const int nk = Klen / BK;

#define STAGE2(buf, kt)                                                                   \
  {                                                                                       \
    _Pragma("unroll")                                                                     \
    for (int g = 0; g < 4; ++g) {                                                         \
      __builtin_amdgcn_global_load_lds(                                                   \
          (const __attribute__((address_space(1))) uint32_t*)(ga[g] + (size_t)(kt) * BK), \
          (__attribute__((address_space(3))) uint32_t*)(&sAB[buf][0][loff[g]]), 16, 0, 0);\
      __builtin_amdgcn_global_load_lds(                                                   \
          (const __attribute__((address_space(1))) uint32_t*)(gb[g] + (size_t)(kt) * BK), \
          (__attribute__((address_space(3))) uint32_t*)(&sAB[buf][1][loff[g]]), 16, 0, 0);\
    }                                                                                     \
  }

  STAGE2(0, 0);
  __syncthreads();

  int cur = 0;
  for (int kt = 0; kt < nk; ++kt) {
    if (kt + 1 < nk) STAGE2(cur ^ 1, kt + 1);
    const uint16_t* pA = &sAB[cur][0][0];
    const uint16_t* pB = &sAB[cur][1][0];
    bf16x8 af[4][2], bb[4][2];
#pragma unroll
    for (int m = 0; m < 4; ++m)
#pragma unroll
      for (int ks = 0; ks < 2; ++ks) {
        const int slot = (ks * 4 + hi) ^ rx;
        af[m][ks] = *reinterpret_cast<const bf16x8*>(pA + (wm + m * 16 + fr) * BK + slot * 8);
        bb[m][ks] = *reinterpret_cast<const bf16x8*>(pB + (wn + m * 16 + fr) * BK + slot * 8);
      }
#pragma unroll
    for (int ks = 0; ks < 2; ++ks)
#pragma unroll
      for (int m = 0; m < 4; ++m)
#pragma unroll
        for (int n = 0; n < 4; ++n)
          acc[m][n] = __builtin_amdgcn_mfma_f32_16x16x32_bf16(af[m][ks], bb[n][ks], acc[m][n], 0, 0, 0);
    __syncthreads();
    cur ^= 1;
  }
#undef STAGE2

  const int cn  = lane & 15;
  const int cm4 = (lane >> 4) * 4;
#pragma unroll
  for (int m = 0; m < 4; ++m) {
#pragma unroll
    for (int n = 0; n < 4; ++n) {
      const int gm = m0 + wm + m * 16 + cm4;
      const int gn = n0 + wn + n * 16 + cn;
      const float bbv = bias ? bias[gn] : 0.f;
#pragma unroll
      for (int r = 0; r < 4; ++r) {
        const size_t idx = (size_t)(gm + r) * N + gn;
        const float vv = acc[m][n][r] + bbv;
        if constexpr (MODE == 0) {
          ((uint16_t*)out)[idx] = f2bf(vv);
        } else {
          ((float*)out)[idx] = vv + res[idx];
        }
      }
    }
  }
}

// ---------------- 8-phase 256x256 GEMM (big GEMMs) ----------------
// Half-tiles per K-tile (BK=64): r0=B.k0 r1=A.k0 r2=B.k1 r3=A.k1, each 256rows x 32k = 16KB.
// Staged one per phase, 7 halves ahead; vmcnt(6) once per K-tile (P3).
// MODE 0: bf16(relu(acc+bias))   MODE 1: bf16(acc) -> out + z*M*N (split-K partial)
template <int MODE>
__launch_bounds__(512, 2)
__global__ void gemm8ph_kernel(const uint16_t* __restrict__ A, const uint16_t* __restrict__ Bt,
                               const float* __restrict__ bias, void* __restrict__ out,
                               int M, int N, int Klen, int lda, int ldb) {
  extern __shared__ uint16_t lds[];   // 2 bufs x 4 regions x 8192 elems = 128 KB
  const int tid  = threadIdx.x;
  const int lane = tid & 63;
  const int wave = tid >> 6;

  const int nwg = gridDim.x * gridDim.y;
  int wg = blockIdx.y * gridDim.x + blockIdx.x;
  wg = (wg & 7) * (nwg >> 3) + (wg >> 3);
  const int bx = wg % gridDim.x, by = wg / gridDim.x;
  const int m0 = by * 256, n0 = bx * 256;

  const int z = blockIdx.z;
  A  += (size_t)z * Klen;
  Bt += (size_t)z * Klen;

  const int wm = (wave >> 2) * 128;       // 2 M-wave-groups
  const int wn = (wave & 3) * 64;         // 4 N-wave-groups

  f32x4 acc[8][4] = {};

  // ---- staging constants: thread handles chunks {tid, tid+512} of each half ----
  const int R0 = tid >> 2;                                      // 0..127 (chunk2: +128)
  const int sg = ((tid & 3) ^ (((tid >> 2) ^ (tid >> 4)) & 3)) * 8;  // inverse-swizzled src slot
  const uint16_t* gA0 = A + (size_t)(m0 + R0) * lda + sg;
  const uint16_t* gA1 = A + (size_t)(m0 + R0 + 128) * lda + sg;
  const uint16_t* gB0 = Bt + (size_t)(n0 + R0) * ldb + sg;
  const uint16_t* gB1 = Bt + (size_t)(n0 + R0 + 128) * ldb + sg;

  const int nk = Klen / 64;

#define STAGE8(T, R)                                                                        \
  if ((T) < nk) {                                                                           \
    const uint16_t* s0 = (((R) & 1) ? gA0 : gB0) + (size_t)(T) * 64 + ((R) >> 1) * 32;      \
    const uint16_t* s1 = (((R) & 1) ? gA1 : gB1) + (size_t)(T) * 64 + ((R) >> 1) * 32;      \
    uint16_t* d = lds + (((T) & 1) * 32768 + (R) * 8192);                                   \
    __builtin_amdgcn_global_load_lds(                                                       \
        (const __attribute__((address_space(1))) uint32_t*)s0,                              \
        (__attribute__((address_space(3))) uint32_t*)(d + (size_t)tid * 8), 16, 0, 0);      \
    __builtin_amdgcn_global_load_lds(                                                       \
        (const __attribute__((address_space(1))) uint32_t*)s1,                              \
        (__attribute__((address_space(3))) uint32_t*)(d + (size_t)(tid + 512) * 8), 16, 0, 0); \
  }

  // ---- read constants ----
  const int fr = lane & 15;
  const int hi = lane >> 4;
  const int g  = (fr ^ (fr >> 2)) & 3;                 // read-side swizzle (row-derived)
  const int laneA = wm * 32 + fr * 32 + ((hi ^ g) * 8);
  const int laneB = wn * 32 + fr * 32 + ((hi ^ g) * 8);

  // ---- prologue: stage 7 halves (tiles 0 + 1.r0-2) ----
  STAGE8(0, 0); STAGE8(0, 1); STAGE8(0, 2); STAGE8(0, 3);
  asm volatile("s_waitcnt vmcnt(4)" ::: "memory");
  STAGE8(1, 0); STAGE8(1, 1); STAGE8(1, 2);
  asm volatile("s_waitcnt vmcnt(6)" ::: "memory");
  __builtin_amdgcn_s_barrier();

#define MFMA16(MB)                                                        \
  __builtin_amdgcn_s_setprio(1);                                          \
  _Pragma("unroll") for (int m = 0; m < 4; ++m)                           \
    _Pragma("unroll") for (int n = 0; n < 4; ++n)                         \
      acc[m + (MB)][n] = __builtin_amdgcn_mfma_f32_16x16x32_bf16(         \
          aq[m], bq[n], acc[m + (MB)][n], 0, 0, 0);                       \
  __builtin_amdgcn_s_setprio(0);

  for (int k = 0; k < nk; ++k) {
    const uint16_t* bufp = lds + (k & 1) * 32768;
    bf16x8 aq[4], bq[4];
    // ---- P0: ks=0, m0-3 ----
#pragma unroll
    for (int n = 0; n < 4; ++n) bq[n] = *reinterpret_cast<const bf16x8*>(bufp + 0 * 8192 + laneB + n * 512);
#pragma unroll
    for (int m = 0; m < 4; ++m) aq[m] = *reinterpret_cast<const bf16x8*>(bufp + 1 * 8192 + laneA + m * 512);
    STAGE8(k + 1, 3);
    __builtin_amdgcn_s_barrier();
    asm volatile("s_waitcnt lgkmcnt(0)" ::: "memory");
    MFMA16(0);
    __builtin_amdgcn_s_barrier();
    // ---- P1: ks=0, m4-7 (bq held) ----
#pragma unroll
    for (int m = 0; m < 4; ++m) aq[m] = *reinterpret_cast<const bf16x8*>(bufp + 1 * 8192 + laneA + (m + 4) * 512);
    STAGE8(k + 2, 0);
    __builtin_amdgcn_s_barrier();
    asm volatile("s_waitcnt lgkmcnt(0)" ::: "memory");
    MFMA16(4);
    __builtin_amdgcn_s_barrier();
    // ---- P2: ks=1, m0-3 ----
#pragma unroll
    for (int n = 0; n < 4; ++n) bq[n] = *reinterpret_cast<const bf16x8*>(bufp + 2 * 8192 + laneB + n * 512);
#pragma unroll
    for (int m = 0; m < 4; ++m) aq[m] = *reinterpret_cast<const bf16x8*>(bufp + 3 * 8192 + laneA + m * 512);
    STAGE8(k + 2, 1);
    __builtin_amdgcn_s_barrier();
    asm volatile("s_waitcnt lgkmcnt(0)" ::: "memory");
    MFMA16(0);
    __builtin_amdgcn_s_barrier();
    // ---- P3: ks=1, m4-7 (bq held) ----
#pragma unroll
    for (int m = 0; m < 4; ++m) aq[m] = *reinterpret_cast<const bf16x8*>(bufp + 3 * 8192 + laneA + (m + 4) * 512);
    STAGE8(k + 2, 2);
    if (k < nk - 2) { asm volatile("s_waitcnt vmcnt(6)" ::: "memory"); }
    else            { asm volatile("s_waitcnt vmcnt(0)" ::: "memory"); }
    __builtin_amdgcn_s_barrier();
    asm volatile("s_waitcnt lgkmcnt(0)" ::: "memory");
    MFMA16(4);
    __builtin_amdgcn_s_barrier();
  }
#undef MFMA16
#undef STAGE8

  // ---- epilogue ----
  const int cn  = lane & 15;
  const int cm4 = (lane >> 4) * 4;
  uint16_t* outp = (uint16_t*)out;
  if constexpr (MODE == 1) outp += (size_t)z * M * N;
  float bias_n[4];
  if constexpr (MODE == 0) {
#pragma unroll
    for (int n = 0; n < 4; ++n) bias_n[n] = bias[n0 + wn + n * 16 + cn];
  }
#pragma unroll
  for (int m = 0; m < 8; ++m) {
#pragma unroll
    for (int n = 0; n < 4; ++n) {
      const int gm = m0 + wm + m * 16 + cm4;
      const int gn = n0 + wn + n * 16 + cn;
#pragma unroll
      for (int r = 0; r < 4; ++r) {
        const size_t idx = (size_t)(gm + r) * N + gn;
        if constexpr (MODE == 0) {
          outp[idx] = f2bf(fmaxf(acc[m][n][r] + bias_n[n], 0.f));
        } else {
          outp[idx] = f2bf(acc[m][n][r]);
        }
      }
    }
  }
}

// ---------------- LN1: hb = bf16(LN(r1)*g + b) ----------------
__global__ void ln1_kernel(const float* __restrict__ in,
                           const float* __restrict__ g,
                           const float* __restrict__ b,
                           uint16_t* __restrict__ outb) {
  const int row = blockIdx.x;
  const int t = threadIdx.x;
  const float4 v = reinterpret_cast<const float4*>(in + (size_t)row * 1024)[t];
  float s  = v.x + v.y + v.z + v.w;
  float s2 = v.x * v.x + v.y * v.y + v.z * v.z + v.w * v.w;
#pragma unroll
  for (int o = 32; o > 0; o >>= 1) { s += __shfl_down(s, o); s2 += __shfl_down(s2, o); }
  __shared__ float red[8];
  const int lane = t & 63, wave = t >> 6;
  if (lane == 0) { red[wave] = s; red[4 + wave] = s2; }
  __syncthreads();
  const float S  = red[0] + red[1] + red[2] + red[3];
  const float S2 = red[4] + red[5] + red[6] + red[7];
  const float mu  = S * (1.f / 1024.f);
  const float var = S2 * (1.f / 1024.f) - mu * mu;
  const float rs  = rsqrtf(var + 1e-5f);
  const float4 gg = reinterpret_cast<const float4*>(g)[t];
  const float4 bb = reinterpret_cast<const float4*>(b)[t];
  ushort4 ob;
  ob.x = f2bf((v.x - mu) * rs * gg.x + bb.x);
  ob.y = f2bf((v.y - mu) * rs * gg.y + bb.y);
  ob.z = f2bf((v.z - mu) * rs * gg.z + bb.z);
  ob.w = f2bf((v.w - mu) * rs * gg.w + bb.w);
  reinterpret_cast<ushort4*>(outb + (size_t)row * 1024)[t] = ob;
}

// ---------------- LN2: out = LN(sum_z pp[z] + b2 + h)*g + be ----------------
__global__ void ln2_kernel(const uint16_t* __restrict__ pp, size_t pstride,
                           const uint16_t* __restrict__ hb, const float* __restrict__ b2,
                           const float* __restrict__ g, const float* __restrict__ be,
                           float* __restrict__ out) {
  const int row = blockIdx.x;
  const int t = threadIdx.x;
  const size_t base = (size_t)row * 1024;
  const ushort4 h4 = reinterpret_cast<const ushort4*>(hb + base)[t];
  const float4 c2 = reinterpret_cast<const float4*>(b2)[t];
  float4 v;
  v.x = c2.x + bf2f(h4.x); v.y = c2.y + bf2f(h4.y);
  v.z = c2.z + bf2f(h4.z); v.w = c2.w + bf2f(h4.w);
#pragma unroll
  for (int zz = 0; zz < 4; ++zz) {
    const ushort4 p4 = reinterpret_cast<const ushort4*>(pp + zz * pstride + base)[t];
    v.x += bf2f(p4.x); v.y += bf2f(p4.y); v.z += bf2f(p4.z); v.w += bf2f(p4.w);
  }
  float s  = v.x + v.y + v.z + v.w;
  float s2 = v.x * v.x + v.y * v.y + v.z * v.z + v.w * v.w;
#pragma unroll
  for (int o = 32; o > 0; o >>= 1) { s += __shfl_down(s, o); s2 += __shfl_down(s2, o); }
  __shared__ float red[8];
  const int lane = t & 63, wave = t >> 6;
  if (lane == 0) { red[wave] = s; red[4 + wave] = s2; }
  __syncthreads();
  const float S  = red[0] + red[1] + red[2] + red[3];
  const float S2 = red[4] + red[5] + red[6] + red[7];
  const float mu  = S * (1.f / 1024.f);
  const float var = S2 * (1.f / 1024.f) - mu * mu;
  const float rs  = rsqrtf(var + 1e-5f);
  const float4 gg = reinterpret_cast<const float4*>(g)[t];
  const float4 bb = reinterpret_cast<const float4*>(be)[t];
  float4 o;
  o.x = (v.x - mu) * rs * gg.x + bb.x;
  o.y = (v.y - mu) * rs * gg.y + bb.y;
  o.z = (v.z - mu) * rs * gg.z + bb.z;
  o.w = (v.w - mu) * rs * gg.w + bb.w;
  reinterpret_cast<float4*>(out + base)[t] = o;
}

// ---------------- launch ----------------
extern "C" void kernel_launch(void* const* d_in, const int* in_sizes, int n_in,
                              void* d_out, int out_size, void* d_ws, size_t ws_size,
                              hipStream_t stream) {
  // hollow attention == identity: out = attn@v = v, so the layer is
  // r1 = x + x@(Wv@Wo) + (bv@Wo+bo); h = LN1(r1); r2 = h + relu(h@W1+b1)@W2 + b2; out = LN2(r2)
  const float* x   = (const float*)d_in[0];
  const float* Wv  = (const float*)d_in[6];
  const float* bv  = (const float*)d_in[7];
  const float* Wo  = (const float*)d_in[8];
  const float* bo  = (const float*)d_in[9];
  const float* W1  = (const float*)d_in[10];
  const float* b1  = (const float*)d_in[11];
  const float* W2  = (const float*)d_in[12];
  const float* b2  = (const float*)d_in[13];
  const float* g1  = (const float*)d_in[14];
  const float* be1 = (const float*)d_in[15];
  const float* g2  = (const float*)d_in[16];
  const float* be2 = (const float*)d_in[17];
  float* out = (float*)d_out;

  constexpr int M = 4096, DM = 1024, FF = 4096;

  char* p = (char*)d_ws;
  auto alloc = [&](size_t bytes) {
    char* r = p;
    p += (bytes + 255) & ~(size_t)255;
    return r;
  };
  uint16_t* xb  = (uint16_t*)alloc((size_t)M * DM * 2);
  uint16_t* wvb = (uint16_t*)alloc((size_t)DM * DM * 2);
  uint16_t* woT = (uint16_t*)alloc((size_t)DM * DM * 2);
  uint16_t* w1t = (uint16_t*)alloc((size_t)FF * DM * 2);
  uint16_t* w2t = (uint16_t*)alloc((size_t)DM * FF * 2);
  uint16_t* wcT = (uint16_t*)alloc((size_t)DM * DM * 2);
  float*    bc  = (float*)   alloc((size_t)DM * 4);
  float*    r1  = (float*)   alloc((size_t)M * DM * 4);
  uint16_t* hb  = (uint16_t*)alloc((size_t)M * DM * 2);
  uint16_t* tb  = (uint16_t*)alloc((size_t)M * FF * 2);
  uint16_t* pp  = (uint16_t*)alloc((size_t)4 * M * DM * 2);  // split-K bf16 partials

  // opt-in to 128 KB dynamic LDS for the 8-phase kernels (host-side, capture-safe)
  (void)hipFuncSetAttribute(reinterpret_cast<const void*>(gemm8ph_kernel<0>),
                            hipFuncAttributeMaxDynamicSharedMemorySize, 131072);
  (void)hipFuncSetAttribute(reinterpret_cast<const void*>(gemm8ph_kernel<1>),
                            hipFuncAttributeMaxDynamicSharedMemorySize, 131072);

  const dim3 tb32(32, 8);

  cvt_bf16_kernel<<<M * DM / 4 / 256, 256, 0, stream>>>(x, xb, M * DM / 4);
  cvt_bf16_kernel<<<DM * DM / 4 / 256, 256, 0, stream>>>(Wv, wvb, DM * DM / 4);
  transpose_cvt_kernel<<<dim3(DM / 32, DM / 32), tb32, 0, stream>>>(Wo, woT, DM, DM);
  transpose_cvt_kernel<<<dim3(FF / 32, DM / 32), tb32, 0, stream>>>(W1, w1t, DM, FF);
  transpose_cvt_kernel<<<dim3(DM / 32, FF / 32), tb32, 0, stream>>>(W2, w2t, FF, DM);
  bc_kernel<<<32, 256, 0, stream>>>(bv, Wo, bo, bc);

  // WcT = (Wv@Wo)^T : C[j][i] = sum_k WoT[j][k] * Wv[i][k]
  gemm2ph_kernel<0><<<dim3(DM / BN, DM / BM), 256, 0, stream>>>(
      woT, wvb, nullptr, nullptr, wcT, DM, DM, DM, DM, DM);
  // r1 = x + x@Wc + bc
  gemm2ph_kernel<1><<<dim3(DM / BN, M / BM), 256, 0, stream>>>(
      xb, wcT, bc, x, r1, M, DM, DM, DM, DM);
  // h = LN1(r1)
  ln1_kernel<<<M, 256, 0, stream>>>(r1, g1, be1, hb);
  // t = relu(h@W1 + b1)   [8-phase 256^2]
  gemm8ph_kernel<0><<<dim3(FF / 256, M / 256), 512, 131072, stream>>>(
      hb, w1t, b1, tb, M, FF, DM, DM, DM);
  // pp[z] = t[:, z*1024:(z+1)*1024] @ W2[z*1024:(z+1)*1024, :]   [8-phase, split-K=4]
  gemm8ph_kernel<1><<<dim3(DM / 256, M / 256, 4), 512, 131072, stream>>>(
      tb, w2t, nullptr, pp, M, DM, FF / 4, FF, FF);
  // out = LN2(h + sum_z pp[z] + b2)
  ln2_kernel<<<M, 256, 0, stream>>>(pp, (size_t)M * DM, hb, b2, g2, be2, out);
}

// Round 4
// 156.078 us; speedup vs baseline: 1.3710x; 1.0381x over previous
//
#include <hip/hip_runtime.h>
#include <stdint.h>

typedef __bf16 bf16x8 __attribute__((ext_vector_type(8)));
typedef float f32x4 __attribute__((ext_vector_type(4)));

__device__ __forceinline__ uint16_t f2bf(float f) {
  union { float f; uint32_t u; } c; c.f = f;
  uint32_t u = c.u;
  u += 0x7fffu + ((u >> 16) & 1u);   // round-to-nearest-even
  return (uint16_t)(u >> 16);
}
__device__ __forceinline__ float bf2f(uint16_t u) {
  union { uint32_t u; float f; } c; c.u = (uint32_t)u << 16; return c.f;
}

// ---------------- fused preamble: cvt x, cvt Wv, 3 transposes, bc ----------------
__device__ __forceinline__ void cvt_body(const float* __restrict__ in,
                                         uint16_t* __restrict__ out, int i) {
  float4 v = reinterpret_cast<const float4*>(in)[i];
  ushort4 o;
  o.x = f2bf(v.x); o.y = f2bf(v.y); o.z = f2bf(v.z); o.w = f2bf(v.w);
  reinterpret_cast<ushort4*>(out)[i] = o;
}

__global__ void prep_kernel(const float* __restrict__ x, const float* __restrict__ Wv,
                            const float* __restrict__ Wo, const float* __restrict__ W1,
                            const float* __restrict__ W2, const float* __restrict__ bv,
                            const float* __restrict__ bo,
                            uint16_t* __restrict__ xb, uint16_t* __restrict__ wvb,
                            uint16_t* __restrict__ woT, uint16_t* __restrict__ w1t,
                            uint16_t* __restrict__ w2t, float* __restrict__ bc) {
  __shared__ float tsh[32][33];
  __shared__ float red[8][32];
  int b = blockIdx.x;
  const int t = threadIdx.x;
  if (b < 4096) { cvt_body(x, xb, b * 256 + t); return; }
  b -= 4096;
  if (b < 1024) { cvt_body(Wv, wvb, b * 256 + t); return; }
  b -= 1024;

  const float* tin = nullptr; uint16_t* tout = nullptr;
  int R = 0, C = 0, bx = 0, by = 0;
  if (b < 1024) {                      // Wo^T: 1024x1024
    tin = Wo; tout = woT; R = 1024; C = 1024; bx = b & 31; by = b >> 5;
  } else if (b < 1024 + 4096) {        // W1^T: [1024,4096] -> [4096,1024]
    const int bb = b - 1024;
    tin = W1; tout = w1t; R = 1024; C = 4096; bx = bb & 127; by = bb >> 7;
  } else if (b < 1024 + 8192) {        // W2^T: [4096,1024] -> [1024,4096]
    const int bb = b - (1024 + 4096);
    tin = W2; tout = w2t; R = 4096; C = 1024; bx = bb & 31; by = bb >> 5;
  } else {                             // bc = bv @ Wo + bo : 32 blocks
    const int jb = b - (1024 + 8192);
    const int jl = t & 31, kg = t >> 5;
    const int j = jb * 32 + jl;
    float s = 0.f;
    const int k0 = kg * 128;
    for (int k = k0; k < k0 + 128; ++k) s += bv[k] * Wo[(size_t)k * 1024 + j];
    red[kg][jl] = s;
    __syncthreads();
    if (kg == 0) {
      float acc = bo[j];
#pragma unroll
      for (int q = 0; q < 8; ++q) acc += red[q][jl];
      bc[j] = acc;
    }
    return;
  }
  // transpose f32 [R,C] -> bf16 [C,R]
  const int tx = t & 31, ty = t >> 5;
  const int c0 = bx * 32, r0 = by * 32;
#pragma unroll
  for (int i = 0; i < 4; ++i)
    tsh[ty + i * 8][tx] = tin[(size_t)(r0 + ty + i * 8) * C + (c0 + tx)];
  __syncthreads();
#pragma unroll
  for (int i = 0; i < 4; ++i)
    tout[(size_t)(c0 + ty + i * 8) * R + (r0 + tx)] = f2bf(tsh[tx][ty + i * 8]);
}

// ---------------- 2-phase 128x128 GEMM (small GEMMs; measured 0 bank conflicts) ----------------
// MODE 0: bf16(acc + bias?)   MODE 1: f32(acc + bias + res)
constexpr int BM = 128, BN = 128, BK = 64;

template <int MODE>
__launch_bounds__(256, 2)
__global__ void gemm2ph_kernel(const uint16_t* __restrict__ A, const uint16_t* __restrict__ Bt,
                               const float* __restrict__ bias, const float* __restrict__ res,
                               void* __restrict__ out, int M, int N, int Klen, int lda, int ldb) {
  __shared__ uint16_t sAB[2][2][BM * BK];
  const int tid  = threadIdx.x;
  const int lane = tid & 63;
  const int wave = tid >> 6;

  const int nwg = gridDim.x * gridDim.y;
  int wg = blockIdx.y * gridDim.x + blockIdx.x;
  wg = (wg & 7) * (nwg >> 3) + (wg >> 3);
  const int bx = wg % gridDim.x, by = wg / gridDim.x;
  const int m0 = by * BM, n0 = bx * BN;

  const int wm = (wave >> 1) * 64;
  const int wn = (wave & 1) * 64;

  f32x4 acc[4][4] = {};

  const int srow = tid >> 3;
  const int scol = ((tid & 7) ^ (srow & 7)) * 8;
  const uint16_t* ga[4];
  const uint16_t* gb[4];
  uint32_t loff[4];
#pragma unroll
  for (int g = 0; g < 4; ++g) {
    const int row = srow + 32 * g;
    ga[g] = A + (size_t)(m0 + row) * lda + scol;
    gb[g] = Bt + (size_t)(n0 + row) * ldb + scol;
    loff[g] = (uint32_t)(tid + g * 256) * 8;
  }

  const int fr = lane & 15;
  const int hi = lane >> 4;
  const int rx = fr & 7;

  const int nk = Klen / BK;

#define STAGE2(buf, kt)                                                                   \
  {                                                                                       \
    _Pragma("unroll")                                                                     \
    for (int g = 0; g < 4; ++g) {                                                         \
      __builtin_amdgcn_global_load_lds(                                                   \
          (const __attribute__((address_space(1))) uint32_t*)(ga[g] + (size_t)(kt) * BK), \
          (__attribute__((address_space(3))) uint32_t*)(&sAB[buf][0][loff[g]]), 16, 0, 0);\
      __builtin_amdgcn_global_load_lds(                                                   \
          (const __attribute__((address_space(1))) uint32_t*)(gb[g] + (size_t)(kt) * BK), \
          (__attribute__((address_space(3))) uint32_t*)(&sAB[buf][1][loff[g]]), 16, 0, 0);\
    }                                                                                     \
  }

  STAGE2(0, 0);
  __syncthreads();

  int cur = 0;
  for (int kt = 0; kt < nk; ++kt) {
    if (kt + 1 < nk) STAGE2(cur ^ 1, kt + 1);
    const uint16_t* pA = &sAB[cur][0][0];
    const uint16_t* pB = &sAB[cur][1][0];
    bf16x8 af[4][2], bb[4][2];
#pragma unroll
    for (int m = 0; m < 4; ++m)
#pragma unroll
      for (int ks = 0; ks < 2; ++ks) {
        const int slot = (ks * 4 + hi) ^ rx;
        af[m][ks] = *reinterpret_cast<const bf16x8*>(pA + (wm + m * 16 + fr) * BK + slot * 8);
        bb[m][ks] = *reinterpret_cast<const bf16x8*>(pB + (wn + m * 16 + fr) * BK + slot * 8);
      }
#pragma unroll
    for (int ks = 0; ks < 2; ++ks)
#pragma unroll
      for (int m = 0; m < 4; ++m)
#pragma unroll
        for (int n = 0; n < 4; ++n)
          acc[m][n] = __builtin_amdgcn_mfma_f32_16x16x32_bf16(af[m][ks], bb[n][ks], acc[m][n], 0, 0, 0);
    __syncthreads();
    cur ^= 1;
  }
#undef STAGE2

  const int cn  = lane & 15;
  const int cm4 = (lane >> 4) * 4;
#pragma unroll
  for (int m = 0; m < 4; ++m) {
#pragma unroll
    for (int n = 0; n < 4; ++n) {
      const int gm = m0 + wm + m * 16 + cm4;
      const int gn = n0 + wn + n * 16 + cn;
      const float bbv = bias ? bias[gn] : 0.f;
#pragma unroll
      for (int r = 0; r < 4; ++r) {
        const size_t idx = (size_t)(gm + r) * N + gn;
        const float vv = acc[m][n][r] + bbv;
        if constexpr (MODE == 0) {
          ((uint16_t*)out)[idx] = f2bf(vv);
        } else {
          ((float*)out)[idx] = vv + res[idx];
        }
      }
    }
  }
}

// ---------------- 8-phase 256x256 GEMM, v2: 128B-row units, m-quadrant phases ----------------
// LDS: 2 bufs x 8 units x [64 rows][64 k] bf16 (128B rows, 3-bit slot key salted by unit).
// Units: U0..U3 = A rows 0-63/64-127/128-191/192-255; U4..U7 = B likewise.
// Phase q reads aq m=2q,2q+1 (both ks); B read entirely at P0, held in regs.
// Stage slots per tile k: P0:[k+1.U0,U2] P1:[k+1.U1,U3] P2:[k+2.U4,U5] P3:[k+2.U6,U7]
// Waits: vmcnt(8) at P1, vmcnt(6) at P3 (tail: 2/0). FIFO ledger verified.
// MODE 0: bf16(relu(acc+bias))   MODE 1: bf16(acc) -> out + z*M*N (split-K partial)
template <int MODE>
__launch_bounds__(512, 2)
__global__ void gemm8ph_kernel(const uint16_t* __restrict__ A, const uint16_t* __restrict__ Bt,
                               const float* __restrict__ bias, void* __restrict__ out,
                               int M, int N, int Klen, int lda, int ldb) {
  extern __shared__ uint16_t lds[];   // 2 x 32768 elems = 128 KB
  const int tid  = threadIdx.x;
  const int lane = tid & 63;
  const int wave = tid >> 6;

  const int nwg = gridDim.x * gridDim.y;
  int wg = blockIdx.y * gridDim.x + blockIdx.x;
  wg = (wg & 7) * (nwg >> 3) + (wg >> 3);
  const int bx = wg % gridDim.x, by = wg / gridDim.x;
  const int m0 = by * 256, n0 = bx * 256;

  const int z = blockIdx.z;
  A  += (size_t)z * Klen;
  Bt += (size_t)z * Klen;

  const int wm = (wave >> 2) * 128;
  const int wn = (wave & 3) * 64;

  f32x4 acc[8][4] = {};

  // ---- staging: thread t stages chunk t of each 8KB unit (row = t>>3, phys slot = t&7) ----
  const int srw = tid >> 3;            // 0..63
  const int sp  = tid & 7;
  const uint16_t* gu[8];
#pragma unroll
  for (int u = 0; u < 8; ++u) {
    const int key = (srw ^ (srw >> 3) ^ u) & 7;
    const uint16_t* base = (u < 4) ? A + (size_t)(m0 + u * 64) * lda
                                   : Bt + (size_t)(n0 + (u - 4) * 64) * ldb;
    const int ld = (u < 4) ? lda : ldb;
    gu[u] = base + (size_t)srw * ld + ((sp ^ key) * 8);
  }

  const int nk = Klen / 64;

#define STAGE8(T, U)                                                                          \
  if ((T) < nk) {                                                                             \
    __builtin_amdgcn_global_load_lds(                                                         \
        (const __attribute__((address_space(1))) uint32_t*)(gu[U] + (size_t)(T) * 64),        \
        (__attribute__((address_space(3))) uint32_t*)(lds + ((T) & 1) * 32768 + (U) * 4096 +  \
                                                      tid * 8),                               \
        16, 0, 0);                                                                            \
  }

  // ---- read offsets (elem, within a 32768-elem tile buffer) ----
  const int fr = lane & 15;
  const int hi = lane >> 4;
  int aoff[8];
#pragma unroll
  for (int m = 0; m < 8; ++m) {
    const int u = (wm >> 6) + (m >> 2);
    const int R = (m & 3) * 16 + fr;
    const int key = (R ^ (R >> 3) ^ u) & 7;
    aoff[m] = u * 4096 + R * 64 + ((hi ^ key) * 8);   // ks=1: XOR 32
  }
  int boff[4];
#pragma unroll
  for (int n = 0; n < 4; ++n) {
    const int u = 4 + (wn >> 6);
    const int R = n * 16 + fr;
    const int key = (R ^ (R >> 3) ^ u) & 7;
    boff[n] = u * 4096 + R * 64 + ((hi ^ key) * 8);
  }

  // ---- prologue: tile 0 (all 8 units) + tile 1's B units; leave 4 in flight ----
  STAGE8(0, 0); STAGE8(0, 2); STAGE8(0, 1); STAGE8(0, 3);
  STAGE8(0, 4); STAGE8(0, 5); STAGE8(0, 6); STAGE8(0, 7);
  STAGE8(1, 4); STAGE8(1, 5); STAGE8(1, 6); STAGE8(1, 7);
  asm volatile("s_waitcnt vmcnt(4)" ::: "memory");
  __builtin_amdgcn_s_barrier();

#define LD8(off) (*reinterpret_cast<const bf16x8*>(bufp + (off)))
#define PHASE_MFMA(q)                                                         \
  __builtin_amdgcn_s_setprio(1);                                              \
  _Pragma("unroll") for (int ks = 0; ks < 2; ++ks)                            \
    _Pragma("unroll") for (int mm = 0; mm < 2; ++mm)                          \
      _Pragma("unroll") for (int n = 0; n < 4; ++n)                           \
        acc[2 * (q) + mm][n] = __builtin_amdgcn_mfma_f32_16x16x32_bf16(       \
            aq[mm][ks], bq[n][ks], acc[2 * (q) + mm][n], 0, 0, 0);            \
  __builtin_amdgcn_s_setprio(0);

  for (int k = 0; k < nk; ++k) {
    const uint16_t* bufp = lds + (k & 1) * 32768;
    bf16x8 bq[4][2], aq[2][2];
    // ---- P0: bq all (held for tile), aq m=0,1 ----
#pragma unroll
    for (int n = 0; n < 4; ++n) { bq[n][0] = LD8(boff[n]); bq[n][1] = LD8(boff[n] ^ 32); }
#pragma unroll
    for (int mm = 0; mm < 2; ++mm) { aq[mm][0] = LD8(aoff[mm]); aq[mm][1] = LD8(aoff[mm] ^ 32); }
    STAGE8(k + 1, 0); STAGE8(k + 1, 2);
    __builtin_amdgcn_s_barrier();
    asm volatile("s_waitcnt lgkmcnt(0)" ::: "memory");
    __builtin_amdgcn_sched_barrier(0);
    PHASE_MFMA(0);
    __builtin_amdgcn_s_barrier();
    // ---- P1: aq m=2,3 ----
#pragma unroll
    for (int mm = 0; mm < 2; ++mm) { aq[mm][0] = LD8(aoff[2 + mm]); aq[mm][1] = LD8(aoff[2 + mm] ^ 32); }
    STAGE8(k + 1, 1); STAGE8(k + 1, 3);
    if (k < nk - 1) { asm volatile("s_waitcnt vmcnt(8)" ::: "memory"); }
    else            { asm volatile("s_waitcnt vmcnt(0)" ::: "memory"); }
    __builtin_amdgcn_s_barrier();
    asm volatile("s_waitcnt lgkmcnt(0)" ::: "memory");
    __builtin_amdgcn_sched_barrier(0);
    PHASE_MFMA(1);
    __builtin_amdgcn_s_barrier();
    // ---- P2: aq m=4,5 ----
#pragma unroll
    for (int mm = 0; mm < 2; ++mm) { aq[mm][0] = LD8(aoff[4 + mm]); aq[mm][1] = LD8(aoff[4 + mm] ^ 32); }
    STAGE8(k + 2, 4); STAGE8(k + 2, 5);
    __builtin_amdgcn_s_barrier();
    asm volatile("s_waitcnt lgkmcnt(0)" ::: "memory");
    __builtin_amdgcn_sched_barrier(0);
    PHASE_MFMA(2);
    __builtin_amdgcn_s_barrier();
    // ---- P3: aq m=6,7 ----
#pragma unroll
    for (int mm = 0; mm < 2; ++mm) { aq[mm][0] = LD8(aoff[6 + mm]); aq[mm][1] = LD8(aoff[6 + mm] ^ 32); }
    STAGE8(k + 2, 6); STAGE8(k + 2, 7);
    if (k < nk - 2)      { asm volatile("s_waitcnt vmcnt(6)" ::: "memory"); }
    else if (k == nk - 2){ asm volatile("s_waitcnt vmcnt(2)" ::: "memory"); }
    else                 { asm volatile("s_waitcnt vmcnt(0)" ::: "memory"); }
    __builtin_amdgcn_s_barrier();
    asm volatile("s_waitcnt lgkmcnt(0)" ::: "memory");
    __builtin_amdgcn_sched_barrier(0);
    PHASE_MFMA(3);
    __builtin_amdgcn_s_barrier();
  }
#undef PHASE_MFMA
#undef LD8
#undef STAGE8

  // ---- epilogue: C/D layout col = lane&15, row = (lane>>4)*4 + reg ----
  const int cn  = lane & 15;
  const int cm4 = (lane >> 4) * 4;
  uint16_t* outp = (uint16_t*)out;
  if constexpr (MODE == 1) outp += (size_t)z * M * N;
  float bias_n[4];
  if constexpr (MODE == 0) {
#pragma unroll
    for (int n = 0; n < 4; ++n) bias_n[n] = bias[n0 + wn + n * 16 + cn];
  }
#pragma unroll
  for (int m = 0; m < 8; ++m) {
#pragma unroll
    for (int n = 0; n < 4; ++n) {
      const int gm = m0 + wm + m * 16 + cm4;
      const int gn = n0 + wn + n * 16 + cn;
#pragma unroll
      for (int r = 0; r < 4; ++r) {
        const size_t idx = (size_t)(gm + r) * N + gn;
        if constexpr (MODE == 0) {
          outp[idx] = f2bf(fmaxf(acc[m][n][r] + bias_n[n], 0.f));
        } else {
          outp[idx] = f2bf(acc[m][n][r]);
        }
      }
    }
  }
}

// ---------------- LN1: hb = bf16(LN(r1)*g + b) ----------------
__global__ void ln1_kernel(const float* __restrict__ in,
                           const float* __restrict__ g,
                           const float* __restrict__ b,
                           uint16_t* __restrict__ outb) {
  const int row = blockIdx.x;
  const int t = threadIdx.x;
  const float4 v = reinterpret_cast<const float4*>(in + (size_t)row * 1024)[t];
  float s  = v.x + v.y + v.z + v.w;
  float s2 = v.x * v.x + v.y * v.y + v.z * v.z + v.w * v.w;
#pragma unroll
  for (int o = 32; o > 0; o >>= 1) { s += __shfl_down(s, o); s2 += __shfl_down(s2, o); }
  __shared__ float red[8];
  const int lane = t & 63, wave = t >> 6;
  if (lane == 0) { red[wave] = s; red[4 + wave] = s2; }
  __syncthreads();
  const float S  = red[0] + red[1] + red[2] + red[3];
  const float S2 = red[4] + red[5] + red[6] + red[7];
  const float mu  = S * (1.f / 1024.f);
  const float var = S2 * (1.f / 1024.f) - mu * mu;
  const float rs  = rsqrtf(var + 1e-5f);
  const float4 gg = reinterpret_cast<const float4*>(g)[t];
  const float4 bb = reinterpret_cast<const float4*>(b)[t];
  ushort4 ob;
  ob.x = f2bf((v.x - mu) * rs * gg.x + bb.x);
  ob.y = f2bf((v.y - mu) * rs * gg.y + bb.y);
  ob.z = f2bf((v.z - mu) * rs * gg.z + bb.z);
  ob.w = f2bf((v.w - mu) * rs * gg.w + bb.w);
  reinterpret_cast<ushort4*>(outb + (size_t)row * 1024)[t] = ob;
}

// ---------------- LN2: out = LN(sum_z pp[z] + b2 + h)*g + be ----------------
__global__ void ln2_kernel(const uint16_t* __restrict__ pp, size_t pstride,
                           const uint16_t* __restrict__ hb, const float* __restrict__ b2,
                           const float* __restrict__ g, const float* __restrict__ be,
                           float* __restrict__ out) {
  const int row = blockIdx.x;
  const int t = threadIdx.x;
  const size_t base = (size_t)row * 1024;
  const ushort4 h4 = reinterpret_cast<const ushort4*>(hb + base)[t];
  const float4 c2 = reinterpret_cast<const float4*>(b2)[t];
  float4 v;
  v.x = c2.x + bf2f(h4.x); v.y = c2.y + bf2f(h4.y);
  v.z = c2.z + bf2f(h4.z); v.w = c2.w + bf2f(h4.w);
#pragma unroll
  for (int zz = 0; zz < 4; ++zz) {
    const ushort4 p4 = reinterpret_cast<const ushort4*>(pp + zz * pstride + base)[t];
    v.x += bf2f(p4.x); v.y += bf2f(p4.y); v.z += bf2f(p4.z); v.w += bf2f(p4.w);
  }
  float s  = v.x + v.y + v.z + v.w;
  float s2 = v.x * v.x + v.y * v.y + v.z * v.z + v.w * v.w;
#pragma unroll
  for (int o = 32; o > 0; o >>= 1) { s += __shfl_down(s, o); s2 += __shfl_down(s2, o); }
  __shared__ float red[8];
  const int lane = t & 63, wave = t >> 6;
  if (lane == 0) { red[wave] = s; red[4 + wave] = s2; }
  __syncthreads();
  const float S  = red[0] + red[1] + red[2] + red[3];
  const float S2 = red[4] + red[5] + red[6] + red[7];
  const float mu  = S * (1.f / 1024.f);
  const float var = S2 * (1.f / 1024.f) - mu * mu;
  const float rs  = rsqrtf(var + 1e-5f);
  const float4 gg = reinterpret_cast<const float4*>(g)[t];
  const float4 bb = reinterpret_cast<const float4*>(be)[t];
  float4 o;
  o.x = (v.x - mu) * rs * gg.x + bb.x;
  o.y = (v.y - mu) * rs * gg.y + bb.y;
  o.z = (v.z - mu) * rs * gg.z + bb.z;
  o.w = (v.w - mu) * rs * gg.w + bb.w;
  reinterpret_cast<float4*>(out + base)[t] = o;
}

// ---------------- launch ----------------
extern "C" void kernel_launch(void* const* d_in, const int* in_sizes, int n_in,
                              void* d_out, int out_size, void* d_ws, size_t ws_size,
                              hipStream_t stream) {
  // hollow attention == identity: out = attn@v = v, so the layer is
  // r1 = x + x@(Wv@Wo) + (bv@Wo+bo); h = LN1(r1); r2 = h + relu(h@W1+b1)@W2 + b2; out = LN2(r2)
  const float* x   = (const float*)d_in[0];
  const float* Wv  = (const float*)d_in[6];
  const float* bv  = (const float*)d_in[7];
  const float* Wo  = (const float*)d_in[8];
  const float* bo  = (const float*)d_in[9];
  const float* W1  = (const float*)d_in[10];
  const float* b1  = (const float*)d_in[11];
  const float* W2  = (const float*)d_in[12];
  const float* b2  = (const float*)d_in[13];
  const float* g1  = (const float*)d_in[14];
  const float* be1 = (const float*)d_in[15];
  const float* g2  = (const float*)d_in[16];
  const float* be2 = (const float*)d_in[17];
  float* out = (float*)d_out;

  constexpr int M = 4096, DM = 1024, FF = 4096;

  char* p = (char*)d_ws;
  auto alloc = [&](size_t bytes) {
    char* r = p;
    p += (bytes + 255) & ~(size_t)255;
    return r;
  };
  uint16_t* xb  = (uint16_t*)alloc((size_t)M * DM * 2);
  uint16_t* wvb = (uint16_t*)alloc((size_t)DM * DM * 2);
  uint16_t* woT = (uint16_t*)alloc((size_t)DM * DM * 2);
  uint16_t* w1t = (uint16_t*)alloc((size_t)FF * DM * 2);
  uint16_t* w2t = (uint16_t*)alloc((size_t)DM * FF * 2);
  uint16_t* wcT = (uint16_t*)alloc((size_t)DM * DM * 2);
  float*    bc  = (float*)   alloc((size_t)DM * 4);
  float*    r1  = (float*)   alloc((size_t)M * DM * 4);
  uint16_t* hb  = (uint16_t*)alloc((size_t)M * DM * 2);
  uint16_t* tb  = (uint16_t*)alloc((size_t)M * FF * 2);
  uint16_t* pp  = (uint16_t*)alloc((size_t)4 * M * DM * 2);  // split-K bf16 partials

  (void)hipFuncSetAttribute(reinterpret_cast<const void*>(gemm8ph_kernel<0>),
                            hipFuncAttributeMaxDynamicSharedMemorySize, 131072);
  (void)hipFuncSetAttribute(reinterpret_cast<const void*>(gemm8ph_kernel<1>),
                            hipFuncAttributeMaxDynamicSharedMemorySize, 131072);

  // fused preamble: cvt x, cvt Wv, Wo^T, W1^T, W2^T, bc  (one launch)
  prep_kernel<<<4096 + 1024 + 1024 + 4096 + 4096 + 32, 256, 0, stream>>>(
      x, Wv, Wo, W1, W2, bv, bo, xb, wvb, woT, w1t, w2t, bc);

  // WcT = (Wv@Wo)^T : C[j][i] = sum_k WoT[j][k] * Wv[i][k]
  gemm2ph_kernel<0><<<dim3(DM / BN, DM / BM), 256, 0, stream>>>(
      woT, wvb, nullptr, nullptr, wcT, DM, DM, DM, DM, DM);
  // r1 = x + x@Wc + bc
  gemm2ph_kernel<1><<<dim3(DM / BN, M / BM), 256, 0, stream>>>(
      xb, wcT, bc, x, r1, M, DM, DM, DM, DM);
  // h = LN1(r1)
  ln1_kernel<<<M, 256, 0, stream>>>(r1, g1, be1, hb);
  // t = relu(h@W1 + b1)   [8-phase v2]
  gemm8ph_kernel<0><<<dim3(FF / 256, M / 256), 512, 131072, stream>>>(
      hb, w1t, b1, tb, M, FF, DM, DM, DM);
  // pp[z] = t[:, z*1024:(z+1)*1024] @ W2[z*1024:(z+1)*1024, :]   [8-phase v2, split-K=4]
  gemm8ph_kernel<1><<<dim3(DM / 256, M / 256, 4), 512, 131072, stream>>>(
      tb, w2t, nullptr, pp, M, DM, FF / 4, FF, FF);
  // out = LN2(h + sum_z pp[z] + b2)
  ln2_kernel<<<M, 256, 0, stream>>>(pp, (size_t)M * DM, hb, b2, g2, be2, out);
}

// Round 5
// 147.456 us; speedup vs baseline: 1.4512x; 1.0585x over previous
//
#include <hip/hip_runtime.h>
#include <stdint.h>

typedef __bf16 bf16x8 __attribute__((ext_vector_type(8)));
typedef float f32x4 __attribute__((ext_vector_type(4)));

__device__ __forceinline__ uint16_t f2bf(float f) {
  union { float f; uint32_t u; } c; c.f = f;
  uint32_t u = c.u;
  u += 0x7fffu + ((u >> 16) & 1u);   // round-to-nearest-even
  return (uint16_t)(u >> 16);
}
__device__ __forceinline__ float bf2f(uint16_t u) {
  union { uint32_t u; float f; } c; c.u = (uint32_t)u << 16; return c.f;
}

// ---------------- fused preamble: cvt x, cvt Wv, 3 transposes, bc ----------------
__device__ __forceinline__ void cvt_body(const float* __restrict__ in,
                                         uint16_t* __restrict__ out, int i) {
  float4 v = reinterpret_cast<const float4*>(in)[i];
  ushort4 o;
  o.x = f2bf(v.x); o.y = f2bf(v.y); o.z = f2bf(v.z); o.w = f2bf(v.w);
  reinterpret_cast<ushort4*>(out)[i] = o;
}

__global__ void prep_kernel(const float* __restrict__ x, const float* __restrict__ Wv,
                            const float* __restrict__ Wo, const float* __restrict__ W1,
                            const float* __restrict__ W2, const float* __restrict__ bv,
                            const float* __restrict__ bo,
                            uint16_t* __restrict__ xb, uint16_t* __restrict__ wvb,
                            uint16_t* __restrict__ woT, uint16_t* __restrict__ w1t,
                            uint16_t* __restrict__ w2t, float* __restrict__ bc) {
  __shared__ float tsh[32][33];
  __shared__ float red[8][32];
  int b = blockIdx.x;
  const int t = threadIdx.x;
  if (b < 4096) { cvt_body(x, xb, b * 256 + t); return; }
  b -= 4096;
  if (b < 1024) { cvt_body(Wv, wvb, b * 256 + t); return; }
  b -= 1024;

  const float* tin = nullptr; uint16_t* tout = nullptr;
  int R = 0, C = 0, bx = 0, by = 0;
  if (b < 1024) {                      // Wo^T: 1024x1024
    tin = Wo; tout = woT; R = 1024; C = 1024; bx = b & 31; by = b >> 5;
  } else if (b < 1024 + 4096) {        // W1^T: [1024,4096] -> [4096,1024]
    const int bb = b - 1024;
    tin = W1; tout = w1t; R = 1024; C = 4096; bx = bb & 127; by = bb >> 7;
  } else if (b < 1024 + 8192) {        // W2^T: [4096,1024] -> [1024,4096]
    const int bb = b - (1024 + 4096);
    tin = W2; tout = w2t; R = 4096; C = 1024; bx = bb & 31; by = bb >> 5;
  } else {                             // bc = bv @ Wo + bo : 32 blocks
    const int jb = b - (1024 + 8192);
    const int jl = t & 31, kg = t >> 5;
    const int j = jb * 32 + jl;
    float s = 0.f;
    const int k0 = kg * 128;
    for (int k = k0; k < k0 + 128; ++k) s += bv[k] * Wo[(size_t)k * 1024 + j];
    red[kg][jl] = s;
    __syncthreads();
    if (kg == 0) {
      float acc = bo[j];
#pragma unroll
      for (int q = 0; q < 8; ++q) acc += red[q][jl];
      bc[j] = acc;
    }
    return;
  }
  const int tx = t & 31, ty = t >> 5;
  const int c0 = bx * 32, r0 = by * 32;
#pragma unroll
  for (int i = 0; i < 4; ++i)
    tsh[ty + i * 8][tx] = tin[(size_t)(r0 + ty + i * 8) * C + (c0 + tx)];
  __syncthreads();
#pragma unroll
  for (int i = 0; i < 4; ++i)
    tout[(size_t)(c0 + ty + i * 8) * R + (r0 + tx)] = f2bf(tsh[tx][ty + i * 8]);
}

// ---------------- 2-phase 128x128 GEMM (small GEMMs; measured 0 bank conflicts) ----------------
// MODE 0: bf16(acc + bias?)   MODE 1: bf16(acc + bias + res_f32)
constexpr int BM = 128, BN = 128, BK = 64;

template <int MODE>
__launch_bounds__(256, 2)
__global__ void gemm2ph_kernel(const uint16_t* __restrict__ A, const uint16_t* __restrict__ Bt,
                               const float* __restrict__ bias, const float* __restrict__ res,
                               void* __restrict__ out, int M, int N, int Klen, int lda, int ldb) {
  __shared__ uint16_t sAB[2][2][BM * BK];
  const int tid  = threadIdx.x;
  const int lane = tid & 63;
  const int wave = tid >> 6;

  const int nwg = gridDim.x * gridDim.y;
  int wg = blockIdx.y * gridDim.x + blockIdx.x;
  wg = (wg & 7) * (nwg >> 3) + (wg >> 3);
  const int bx = wg % gridDim.x, by = wg / gridDim.x;
  const int m0 = by * BM, n0 = bx * BN;

  const int wm = (wave >> 1) * 64;
  const int wn = (wave & 1) * 64;

  f32x4 acc[4][4] = {};

  const int srow = tid >> 3;
  const int scol = ((tid & 7) ^ (srow & 7)) * 8;
  const uint16_t* ga[4];
  const uint16_t* gb[4];
  uint32_t loff[4];
#pragma unroll
  for (int g = 0; g < 4; ++g) {
    const int row = srow + 32 * g;
    ga[g] = A + (size_t)(m0 + row) * lda + scol;
    gb[g] = Bt + (size_t)(n0 + row) * ldb + scol;
    loff[g] = (uint32_t)(tid + g * 256) * 8;
  }

  const int fr = lane & 15;
  const int hi = lane >> 4;
  const int rx = fr & 7;

  const int nk = Klen / BK;

#define STAGE2(buf, kt)                                                                   \
  {                                                                                       \
    _Pragma("unroll")                                                                     \
    for (int g = 0; g < 4; ++g) {                                                         \
      __builtin_amdgcn_global_load_lds(                                                   \
          (const __attribute__((address_space(1))) uint32_t*)(ga[g] + (size_t)(kt) * BK), \
          (__attribute__((address_space(3))) uint32_t*)(&sAB[buf][0][loff[g]]), 16, 0, 0);\
      __builtin_amdgcn_global_load_lds(                                                   \
          (const __attribute__((address_space(1))) uint32_t*)(gb[g] + (size_t)(kt) * BK), \
          (__attribute__((address_space(3))) uint32_t*)(&sAB[buf][1][loff[g]]), 16, 0, 0);\
    }                                                                                     \
  }

  STAGE2(0, 0);
  __syncthreads();

  int cur = 0;
  for (int kt = 0; kt < nk; ++kt) {
    if (kt + 1 < nk) STAGE2(cur ^ 1, kt + 1);
    const uint16_t* pA = &sAB[cur][0][0];
    const uint16_t* pB = &sAB[cur][1][0];
    bf16x8 af[4][2], bb[4][2];
#pragma unroll
    for (int m = 0; m < 4; ++m)
#pragma unroll
      for (int ks = 0; ks < 2; ++ks) {
        const int slot = (ks * 4 + hi) ^ rx;
        af[m][ks] = *reinterpret_cast<const bf16x8*>(pA + (wm + m * 16 + fr) * BK + slot * 8);
        bb[m][ks] = *reinterpret_cast<const bf16x8*>(pB + (wn + m * 16 + fr) * BK + slot * 8);
      }
#pragma unroll
    for (int ks = 0; ks < 2; ++ks)
#pragma unroll
      for (int m = 0; m < 4; ++m)
#pragma unroll
        for (int n = 0; n < 4; ++n)
          acc[m][n] = __builtin_amdgcn_mfma_f32_16x16x32_bf16(af[m][ks], bb[n][ks], acc[m][n], 0, 0, 0);
    __syncthreads();
    cur ^= 1;
  }
#undef STAGE2

  const int cn  = lane & 15;
  const int cm4 = (lane >> 4) * 4;
#pragma unroll
  for (int m = 0; m < 4; ++m) {
#pragma unroll
    for (int n = 0; n < 4; ++n) {
      const int gm = m0 + wm + m * 16 + cm4;
      const int gn = n0 + wn + n * 16 + cn;
      const float bbv = bias ? bias[gn] : 0.f;
#pragma unroll
      for (int r = 0; r < 4; ++r) {
        const size_t idx = (size_t)(gm + r) * N + gn;
        const float vv = acc[m][n][r] + bbv;
        if constexpr (MODE == 0) {
          ((uint16_t*)out)[idx] = f2bf(vv);
        } else {
          ((uint16_t*)out)[idx] = f2bf(vv + res[idx]);
        }
      }
    }
  }
}

// ---------------- 8-phase 256x256 GEMM, v3: r2's empirically-0-conflict swizzle ----------------
// LDS: 2 bufs x 8 units x [64 rows][64 k] bf16. key = row&7 (r2's), slot = colgroup ^ key.
// Units: U0..U3 = A rows 0-63/64-127/128-191/192-255; U4..U7 = B likewise.
// Phases (ks-split): P0: ks0 m0-3 (+bq ks0 read, held), P1: ks0 m4-7,
//                    P2: ks1 m0-3 (+bq ks1), P3: ks1 m4-7.   8/4/8/4 ds_reads.
// Stage slots per tile k: P0:[k+1.U0,U2] P1:[k+1.U1,U3] P2:[k+2.U4,U5] P3:[k+2.U6,U7]
// Waits: vmcnt(8)@P1 (guarantees tile k A_hi), vmcnt(6)@P3 (tile k+1 B+A_lo). Tail 0/2/0.
// MODE 0: bf16(relu(acc+bias))   MODE 1: bf16(acc) -> out + z*M*N (split-K partial)
template <int MODE>
__launch_bounds__(512, 2)
__global__ void gemm8ph_kernel(const uint16_t* __restrict__ A, const uint16_t* __restrict__ Bt,
                               const float* __restrict__ bias, void* __restrict__ out,
                               int M, int N, int Klen, int lda, int ldb) {
  extern __shared__ uint16_t lds[];   // 2 x 32768 elems = 128 KB
  const int tid  = threadIdx.x;
  const int lane = tid & 63;
  const int wave = tid >> 6;

  const int nwg = gridDim.x * gridDim.y;
  int wg = blockIdx.y * gridDim.x + blockIdx.x;
  wg = (wg & 7) * (nwg >> 3) + (wg >> 3);
  const int bx = wg % gridDim.x, by = wg / gridDim.x;
  const int m0 = by * 256, n0 = bx * 256;

  const int z = blockIdx.z;
  A  += (size_t)z * Klen;
  Bt += (size_t)z * Klen;

  const int wm = (wave >> 2) * 128;
  const int wn = (wave & 3) * 64;

  f32x4 acc[8][4] = {};

  // ---- staging: thread t stages chunk t of each 8KB unit (row = t>>3, phys slot = t&7) ----
  const int srw = tid >> 3;            // 0..63
  const int sp  = tid & 7;
  const uint16_t* gu[8];
#pragma unroll
  for (int u = 0; u < 8; ++u) {
    const uint16_t* base = (u < 4) ? A + (size_t)(m0 + u * 64) * lda
                                   : Bt + (size_t)(n0 + (u - 4) * 64) * ldb;
    const int ld = (u < 4) ? lda : ldb;
    gu[u] = base + (size_t)srw * ld + ((sp ^ (srw & 7)) * 8);   // r2 key: row&7
  }

  const int nk = Klen / 64;

#define STAGE8(T, U)                                                                          \
  if ((T) < nk) {                                                                             \
    __builtin_amdgcn_global_load_lds(                                                         \
        (const __attribute__((address_space(1))) uint32_t*)(gu[U] + (size_t)(T) * 64),        \
        (__attribute__((address_space(3))) uint32_t*)(lds + ((T) & 1) * 32768 + (U) * 4096 +  \
                                                      tid * 8),                               \
        16, 0, 0);                                                                            \
  }

  // ---- read offsets (elem, within a 32768-elem tile buffer); ks=1 via ^32 ----
  const int fr = lane & 15;
  const int hi = lane >> 4;
  int aoff[8];
#pragma unroll
  for (int m = 0; m < 8; ++m) {
    const int u = (wm >> 6) + (m >> 2);
    const int R = (m & 3) * 16 + fr;
    aoff[m] = u * 4096 + R * 64 + ((hi ^ (R & 7)) * 8);   // slot = cg ^ (row&7), cg=hi (ks0)
  }
  int boff[4];
#pragma unroll
  for (int n = 0; n < 4; ++n) {
    const int u = 4 + (wn >> 6);
    const int R = n * 16 + fr;
    boff[n] = u * 4096 + R * 64 + ((hi ^ (R & 7)) * 8);
  }

  // ---- prologue: tile 0 (all 8 units) + tile 1's B units; leave 4 in flight ----
  STAGE8(0, 0); STAGE8(0, 2); STAGE8(0, 1); STAGE8(0, 3);
  STAGE8(0, 4); STAGE8(0, 5); STAGE8(0, 6); STAGE8(0, 7);
  STAGE8(1, 4); STAGE8(1, 5); STAGE8(1, 6); STAGE8(1, 7);
  asm volatile("s_waitcnt vmcnt(4)" ::: "memory");
  __builtin_amdgcn_s_barrier();

#define LD8(off) (*reinterpret_cast<const bf16x8*>(bufp + (off)))
#define PHASE_MFMA(MB)                                                        \
  __builtin_amdgcn_s_setprio(1);                                              \
  _Pragma("unroll") for (int mm = 0; mm < 4; ++mm)                            \
    _Pragma("unroll") for (int n = 0; n < 4; ++n)                             \
      acc[(MB) + mm][n] = __builtin_amdgcn_mfma_f32_16x16x32_bf16(            \
          aq[mm], bq[n], acc[(MB) + mm][n], 0, 0, 0);                         \
  __builtin_amdgcn_s_setprio(0);

  for (int k = 0; k < nk; ++k) {
    const uint16_t* bufp = lds + (k & 1) * 32768;
    bf16x8 bq[4], aq[4];
    // ---- P0: ks0, m0-3 (bq ks0 read, held thru P1) ----
#pragma unroll
    for (int n = 0; n < 4; ++n) bq[n] = LD8(boff[n]);
#pragma unroll
    for (int mm = 0; mm < 4; ++mm) aq[mm] = LD8(aoff[mm]);
    STAGE8(k + 1, 0); STAGE8(k + 1, 2);
    __builtin_amdgcn_s_barrier();
    asm volatile("s_waitcnt lgkmcnt(0)" ::: "memory");
    __builtin_amdgcn_sched_barrier(0);
    PHASE_MFMA(0);
    __builtin_amdgcn_s_barrier();
    // ---- P1: ks0, m4-7 ----
#pragma unroll
    for (int mm = 0; mm < 4; ++mm) aq[mm] = LD8(aoff[4 + mm]);
    STAGE8(k + 1, 1); STAGE8(k + 1, 3);
    if (k < nk - 1) { asm volatile("s_waitcnt vmcnt(8)" ::: "memory"); }
    else            { asm volatile("s_waitcnt vmcnt(0)" ::: "memory"); }
    __builtin_amdgcn_s_barrier();
    asm volatile("s_waitcnt lgkmcnt(0)" ::: "memory");
    __builtin_amdgcn_sched_barrier(0);
    PHASE_MFMA(4);
    __builtin_amdgcn_s_barrier();
    // ---- P2: ks1, m0-3 ----
#pragma unroll
    for (int n = 0; n < 4; ++n) bq[n] = LD8(boff[n] ^ 32);
#pragma unroll
    for (int mm = 0; mm < 4; ++mm) aq[mm] = LD8(aoff[mm] ^ 32);
    STAGE8(k + 2, 4); STAGE8(k + 2, 5);
    __builtin_amdgcn_s_barrier();
    asm volatile("s_waitcnt lgkmcnt(0)" ::: "memory");
    __builtin_amdgcn_sched_barrier(0);
    PHASE_MFMA(0);
    __builtin_amdgcn_s_barrier();
    // ---- P3: ks1, m4-7 ----
#pragma unroll
    for (int mm = 0; mm < 4; ++mm) aq[mm] = LD8(aoff[4 + mm] ^ 32);
    STAGE8(k + 2, 6); STAGE8(k + 2, 7);
    if (k < nk - 2)      { asm volatile("s_waitcnt vmcnt(6)" ::: "memory"); }
    else if (k == nk - 2){ asm volatile("s_waitcnt vmcnt(2)" ::: "memory"); }
    else                 { asm volatile("s_waitcnt vmcnt(0)" ::: "memory"); }
    __builtin_amdgcn_s_barrier();
    asm volatile("s_waitcnt lgkmcnt(0)" ::: "memory");
    __builtin_amdgcn_sched_barrier(0);
    PHASE_MFMA(4);
    __builtin_amdgcn_s_barrier();
  }
#undef PHASE_MFMA
#undef LD8
#undef STAGE8

  // ---- epilogue: C/D layout col = lane&15, row = (lane>>4)*4 + reg ----
  const int cn  = lane & 15;
  const int cm4 = (lane >> 4) * 4;
  uint16_t* outp = (uint16_t*)out;
  if constexpr (MODE == 1) outp += (size_t)z * M * N;
  float bias_n[4];
  if constexpr (MODE == 0) {
#pragma unroll
    for (int n = 0; n < 4; ++n) bias_n[n] = bias[n0 + wn + n * 16 + cn];
  }
#pragma unroll
  for (int m = 0; m < 8; ++m) {
#pragma unroll
    for (int n = 0; n < 4; ++n) {
      const int gm = m0 + wm + m * 16 + cm4;
      const int gn = n0 + wn + n * 16 + cn;
#pragma unroll
      for (int r = 0; r < 4; ++r) {
        const size_t idx = (size_t)(gm + r) * N + gn;
        if constexpr (MODE == 0) {
          outp[idx] = f2bf(fmaxf(acc[m][n][r] + bias_n[n], 0.f));
        } else {
          outp[idx] = f2bf(acc[m][n][r]);
        }
      }
    }
  }
}

// ---------------- LN1: hb = bf16(LN(r1b)*g + b), r1b is bf16 ----------------
__global__ void ln1_kernel(const uint16_t* __restrict__ in,
                           const float* __restrict__ g,
                           const float* __restrict__ b,
                           uint16_t* __restrict__ outb) {
  const int row = blockIdx.x;
  const int t = threadIdx.x;
  const ushort4 r4 = reinterpret_cast<const ushort4*>(in + (size_t)row * 1024)[t];
  float4 v;
  v.x = bf2f(r4.x); v.y = bf2f(r4.y); v.z = bf2f(r4.z); v.w = bf2f(r4.w);
  float s  = v.x + v.y + v.z + v.w;
  float s2 = v.x * v.x + v.y * v.y + v.z * v.z + v.w * v.w;
#pragma unroll
  for (int o = 32; o > 0; o >>= 1) { s += __shfl_down(s, o); s2 += __shfl_down(s2, o); }
  __shared__ float red[8];
  const int lane = t & 63, wave = t >> 6;
  if (lane == 0) { red[wave] = s; red[4 + wave] = s2; }
  __syncthreads();
  const float S  = red[0] + red[1] + red[2] + red[3];
  const float S2 = red[4] + red[5] + red[6] + red[7];
  const float mu  = S * (1.f / 1024.f);
  const float var = S2 * (1.f / 1024.f) - mu * mu;
  const float rs  = rsqrtf(var + 1e-5f);
  const float4 gg = reinterpret_cast<const float4*>(g)[t];
  const float4 bb = reinterpret_cast<const float4*>(b)[t];
  ushort4 ob;
  ob.x = f2bf((v.x - mu) * rs * gg.x + bb.x);
  ob.y = f2bf((v.y - mu) * rs * gg.y + bb.y);
  ob.z = f2bf((v.z - mu) * rs * gg.z + bb.z);
  ob.w = f2bf((v.w - mu) * rs * gg.w + bb.w);
  reinterpret_cast<ushort4*>(outb + (size_t)row * 1024)[t] = ob;
}

// ---------------- LN2: out = LN(sum_z pp[z] + b2 + h)*g + be ----------------
__global__ void ln2_kernel(const uint16_t* __restrict__ pp, size_t pstride,
                           const uint16_t* __restrict__ hb, const float* __restrict__ b2,
                           const float* __restrict__ g, const float* __restrict__ be,
                           float* __restrict__ out) {
  const int row = blockIdx.x;
  const int t = threadIdx.x;
  const size_t base = (size_t)row * 1024;
  const ushort4 h4 = reinterpret_cast<const ushort4*>(hb + base)[t];
  const float4 c2 = reinterpret_cast<const float4*>(b2)[t];
  float4 v;
  v.x = c2.x + bf2f(h4.x); v.y = c2.y + bf2f(h4.y);
  v.z = c2.z + bf2f(h4.z); v.w = c2.w + bf2f(h4.w);
#pragma unroll
  for (int zz = 0; zz < 4; ++zz) {
    const ushort4 p4 = reinterpret_cast<const ushort4*>(pp + zz * pstride + base)[t];
    v.x += bf2f(p4.x); v.y += bf2f(p4.y); v.z += bf2f(p4.z); v.w += bf2f(p4.w);
  }
  float s  = v.x + v.y + v.z + v.w;
  float s2 = v.x * v.x + v.y * v.y + v.z * v.z + v.w * v.w;
#pragma unroll
  for (int o = 32; o > 0; o >>= 1) { s += __shfl_down(s, o); s2 += __shfl_down(s2, o); }
  __shared__ float red[8];
  const int lane = t & 63, wave = t >> 6;
  if (lane == 0) { red[wave] = s; red[4 + wave] = s2; }
  __syncthreads();
  const float S  = red[0] + red[1] + red[2] + red[3];
  const float S2 = red[4] + red[5] + red[6] + red[7];
  const float mu  = S * (1.f / 1024.f);
  const float var = S2 * (1.f / 1024.f) - mu * mu;
  const float rs  = rsqrtf(var + 1e-5f);
  const float4 gg = reinterpret_cast<const float4*>(g)[t];
  const float4 bb = reinterpret_cast<const float4*>(be)[t];
  float4 o;
  o.x = (v.x - mu) * rs * gg.x + bb.x;
  o.y = (v.y - mu) * rs * gg.y + bb.y;
  o.z = (v.z - mu) * rs * gg.z + bb.z;
  o.w = (v.w - mu) * rs * gg.w + bb.w;
  reinterpret_cast<float4*>(out + base)[t] = o;
}

// ---------------- launch ----------------
extern "C" void kernel_launch(void* const* d_in, const int* in_sizes, int n_in,
                              void* d_out, int out_size, void* d_ws, size_t ws_size,
                              hipStream_t stream) {
  // hollow attention == identity: out = attn@v = v, so the layer is
  // r1 = x + x@(Wv@Wo) + (bv@Wo+bo); h = LN1(r1); r2 = h + relu(h@W1+b1)@W2 + b2; out = LN2(r2)
  const float* x   = (const float*)d_in[0];
  const float* Wv  = (const float*)d_in[6];
  const float* bv  = (const float*)d_in[7];
  const float* Wo  = (const float*)d_in[8];
  const float* bo  = (const float*)d_in[9];
  const float* W1  = (const float*)d_in[10];
  const float* b1  = (const float*)d_in[11];
  const float* W2  = (const float*)d_in[12];
  const float* b2  = (const float*)d_in[13];
  const float* g1  = (const float*)d_in[14];
  const float* be1 = (const float*)d_in[15];
  const float* g2  = (const float*)d_in[16];
  const float* be2 = (const float*)d_in[17];
  float* out = (float*)d_out;

  constexpr int M = 4096, DM = 1024, FF = 4096;

  char* p = (char*)d_ws;
  auto alloc = [&](size_t bytes) {
    char* r = p;
    p += (bytes + 255) & ~(size_t)255;
    return r;
  };
  uint16_t* xb  = (uint16_t*)alloc((size_t)M * DM * 2);
  uint16_t* wvb = (uint16_t*)alloc((size_t)DM * DM * 2);
  uint16_t* woT = (uint16_t*)alloc((size_t)DM * DM * 2);
  uint16_t* w1t = (uint16_t*)alloc((size_t)FF * DM * 2);
  uint16_t* w2t = (uint16_t*)alloc((size_t)DM * FF * 2);
  uint16_t* wcT = (uint16_t*)alloc((size_t)DM * DM * 2);
  float*    bc  = (float*)   alloc((size_t)DM * 4);
  uint16_t* r1b = (uint16_t*)alloc((size_t)M * DM * 2);
  uint16_t* hb  = (uint16_t*)alloc((size_t)M * DM * 2);
  uint16_t* tb  = (uint16_t*)alloc((size_t)M * FF * 2);
  uint16_t* pp  = (uint16_t*)alloc((size_t)4 * M * DM * 2);  // split-K bf16 partials

  (void)hipFuncSetAttribute(reinterpret_cast<const void*>(gemm8ph_kernel<0>),
                            hipFuncAttributeMaxDynamicSharedMemorySize, 131072);
  (void)hipFuncSetAttribute(reinterpret_cast<const void*>(gemm8ph_kernel<1>),
                            hipFuncAttributeMaxDynamicSharedMemorySize, 131072);

  // fused preamble: cvt x, cvt Wv, Wo^T, W1^T, W2^T, bc  (one launch)
  prep_kernel<<<4096 + 1024 + 1024 + 4096 + 4096 + 32, 256, 0, stream>>>(
      x, Wv, Wo, W1, W2, bv, bo, xb, wvb, woT, w1t, w2t, bc);

  // WcT = (Wv@Wo)^T : C[j][i] = sum_k WoT[j][k] * Wv[i][k]
  gemm2ph_kernel<0><<<dim3(DM / BN, DM / BM), 256, 0, stream>>>(
      woT, wvb, nullptr, nullptr, wcT, DM, DM, DM, DM, DM);
  // r1b = bf16(x + x@Wc + bc)
  gemm2ph_kernel<1><<<dim3(DM / BN, M / BM), 256, 0, stream>>>(
      xb, wcT, bc, x, r1b, M, DM, DM, DM, DM);
  // h = LN1(r1b)
  ln1_kernel<<<M, 256, 0, stream>>>(r1b, g1, be1, hb);
  // t = relu(h@W1 + b1)   [8-phase v3]
  gemm8ph_kernel<0><<<dim3(FF / 256, M / 256), 512, 131072, stream>>>(
      hb, w1t, b1, tb, M, FF, DM, DM, DM);
  // pp[z] = t[:, z*1024:(z+1)*1024] @ W2[z*1024:(z+1)*1024, :]   [8-phase v3, split-K=4]
  gemm8ph_kernel<1><<<dim3(DM / 256, M / 256, 4), 512, 131072, stream>>>(
      tb, w2t, nullptr, pp, M, DM, FF / 4, FF, FF);
  // out = LN2(h + sum_z pp[z] + b2)
  ln2_kernel<<<M, 256, 0, stream>>>(pp, (size_t)M * DM, hb, b2, g2, be2, out);
}

// Round 6
// 145.307 us; speedup vs baseline: 1.4726x; 1.0148x over previous
//
#include <hip/hip_runtime.h>
#include <stdint.h>

typedef __bf16 bf16x8 __attribute__((ext_vector_type(8)));
typedef float f32x4 __attribute__((ext_vector_type(4)));

__device__ __forceinline__ uint16_t f2bf(float f) {
  union { float f; uint32_t u; } c; c.f = f;
  uint32_t u = c.u;
  u += 0x7fffu + ((u >> 16) & 1u);   // round-to-nearest-even
  return (uint16_t)(u >> 16);
}
__device__ __forceinline__ float bf2f(uint16_t u) {
  union { uint32_t u; float f; } c; c.u = (uint32_t)u << 16; return c.f;
}

// ---------------- fused preamble: cvt x, cvt Wv, 3 transposes, bc ----------------
__device__ __forceinline__ void cvt_body(const float* __restrict__ in,
                                         uint16_t* __restrict__ out, int i) {
  float4 v = reinterpret_cast<const float4*>(in)[i];
  ushort4 o;
  o.x = f2bf(v.x); o.y = f2bf(v.y); o.z = f2bf(v.z); o.w = f2bf(v.w);
  reinterpret_cast<ushort4*>(out)[i] = o;
}

__global__ void prep_kernel(const float* __restrict__ x, const float* __restrict__ Wv,
                            const float* __restrict__ Wo, const float* __restrict__ W1,
                            const float* __restrict__ W2, const float* __restrict__ bv,
                            const float* __restrict__ bo,
                            uint16_t* __restrict__ xb, uint16_t* __restrict__ wvb,
                            uint16_t* __restrict__ woT, uint16_t* __restrict__ w1t,
                            uint16_t* __restrict__ w2t, float* __restrict__ bc) {
  __shared__ float tsh[32][33];
  __shared__ float red[8][32];
  int b = blockIdx.x;
  const int t = threadIdx.x;
  if (b < 4096) { cvt_body(x, xb, b * 256 + t); return; }
  b -= 4096;
  if (b < 1024) { cvt_body(Wv, wvb, b * 256 + t); return; }
  b -= 1024;

  const float* tin = nullptr; uint16_t* tout = nullptr;
  int R = 0, C = 0, bx = 0, by = 0;
  if (b < 1024) {                      // Wo^T: 1024x1024
    tin = Wo; tout = woT; R = 1024; C = 1024; bx = b & 31; by = b >> 5;
  } else if (b < 1024 + 4096) {        // W1^T: [1024,4096] -> [4096,1024]
    const int bb = b - 1024;
    tin = W1; tout = w1t; R = 1024; C = 4096; bx = bb & 127; by = bb >> 7;
  } else if (b < 1024 + 8192) {        // W2^T: [4096,1024] -> [1024,4096]
    const int bb = b - (1024 + 4096);
    tin = W2; tout = w2t; R = 4096; C = 1024; bx = bb & 31; by = bb >> 5;
  } else {                             // bc = bv @ Wo + bo : 32 blocks
    const int jb = b - (1024 + 8192);
    const int jl = t & 31, kg = t >> 5;
    const int j = jb * 32 + jl;
    float s = 0.f;
    const int k0 = kg * 128;
    for (int k = k0; k < k0 + 128; ++k) s += bv[k] * Wo[(size_t)k * 1024 + j];
    red[kg][jl] = s;
    __syncthreads();
    if (kg == 0) {
      float acc = bo[j];
#pragma unroll
      for (int q = 0; q < 8; ++q) acc += red[q][jl];
      bc[j] = acc;
    }
    return;
  }
  const int tx = t & 31, ty = t >> 5;
  const int c0 = bx * 32, r0 = by * 32;
#pragma unroll
  for (int i = 0; i < 4; ++i)
    tsh[ty + i * 8][tx] = tin[(size_t)(r0 + ty + i * 8) * C + (c0 + tx)];
  __syncthreads();
#pragma unroll
  for (int i = 0; i < 4; ++i)
    tout[(size_t)(c0 + ty + i * 8) * R + (r0 + tx)] = f2bf(tsh[tx][ty + i * 8]);
}

// ---------------- 2-phase 128x128 GEMM (small GEMMs; measured 0 bank conflicts) ----------------
// MODE 0: bf16(acc + bias?)   MODE 1: bf16(acc + bias + res_f32)
constexpr int BM = 128, BN = 128, BK = 64;

template <int MODE>
__launch_bounds__(256, 2)
__global__ void gemm2ph_kernel(const uint16_t* __restrict__ A, const uint16_t* __restrict__ Bt,
                               const float* __restrict__ bias, const float* __restrict__ res,
                               void* __restrict__ out, int M, int N, int Klen, int lda, int ldb) {
  __shared__ uint16_t sAB[2][2][BM * BK];
  const int tid  = threadIdx.x;
  const int lane = tid & 63;
  const int wave = tid >> 6;

  const int nwg = gridDim.x * gridDim.y;
  int wg = blockIdx.y * gridDim.x + blockIdx.x;
  wg = (wg & 7) * (nwg >> 3) + (wg >> 3);
  const int bx = wg % gridDim.x, by = wg / gridDim.x;
  const int m0 = by * BM, n0 = bx * BN;

  const int wm = (wave >> 1) * 64;
  const int wn = (wave & 1) * 64;

  f32x4 acc[4][4] = {};

  const int srow = tid >> 3;
  const int scol = ((tid & 7) ^ (srow & 7)) * 8;
  const uint16_t* ga[4];
  const uint16_t* gb[4];
  uint32_t loff[4];
#pragma unroll
  for (int g = 0; g < 4; ++g) {
    const int row = srow + 32 * g;
    ga[g] = A + (size_t)(m0 + row) * lda + scol;
    gb[g] = Bt + (size_t)(n0 + row) * ldb + scol;
    loff[g] = (uint32_t)(tid + g * 256) * 8;
  }

  const int fr = lane & 15;
  const int hi = lane >> 4;
  const int rx = fr & 7;

  const int nk = Klen / BK;

#define STAGE2(buf, kt)                                                                   \
  {                                                                                       \
    _Pragma("unroll")                                                                     \
    for (int g = 0; g < 4; ++g) {                                                         \
      __builtin_amdgcn_global_load_lds(                                                   \
          (const __attribute__((address_space(1))) uint32_t*)(ga[g] + (size_t)(kt) * BK), \
          (__attribute__((address_space(3))) uint32_t*)(&sAB[buf][0][loff[g]]), 16, 0, 0);\
      __builtin_amdgcn_global_load_lds(                                                   \
          (const __attribute__((address_space(1))) uint32_t*)(gb[g] + (size_t)(kt) * BK), \
          (__attribute__((address_space(3))) uint32_t*)(&sAB[buf][1][loff[g]]), 16, 0, 0);\
    }                                                                                     \
  }

  STAGE2(0, 0);
  __syncthreads();

  int cur = 0;
  for (int kt = 0; kt < nk; ++kt) {
    if (kt + 1 < nk) STAGE2(cur ^ 1, kt + 1);
    const uint16_t* pA = &sAB[cur][0][0];
    const uint16_t* pB = &sAB[cur][1][0];
    bf16x8 af[4][2], bb[4][2];
#pragma unroll
    for (int m = 0; m < 4; ++m)
#pragma unroll
      for (int ks = 0; ks < 2; ++ks) {
        const int slot = (ks * 4 + hi) ^ rx;
        af[m][ks] = *reinterpret_cast<const bf16x8*>(pA + (wm + m * 16 + fr) * BK + slot * 8);
        bb[m][ks] = *reinterpret_cast<const bf16x8*>(pB + (wn + m * 16 + fr) * BK + slot * 8);
      }
#pragma unroll
    for (int ks = 0; ks < 2; ++ks)
#pragma unroll
      for (int m = 0; m < 4; ++m)
#pragma unroll
        for (int n = 0; n < 4; ++n)
          acc[m][n] = __builtin_amdgcn_mfma_f32_16x16x32_bf16(af[m][ks], bb[n][ks], acc[m][n], 0, 0, 0);
    __syncthreads();
    cur ^= 1;
  }
#undef STAGE2

  const int cn  = lane & 15;
  const int cm4 = (lane >> 4) * 4;
#pragma unroll
  for (int m = 0; m < 4; ++m) {
#pragma unroll
    for (int n = 0; n < 4; ++n) {
      const int gm = m0 + wm + m * 16 + cm4;
      const int gn = n0 + wn + n * 16 + cn;
      const float bbv = bias ? bias[gn] : 0.f;
#pragma unroll
      for (int r = 0; r < 4; ++r) {
        const size_t idx = (size_t)(gm + r) * N + gn;
        const float vv = acc[m][n][r] + bbv;
        if constexpr (MODE == 0) {
          ((uint16_t*)out)[idx] = f2bf(vv);
        } else {
          ((uint16_t*)out)[idx] = f2bf(vv + res[idx]);
        }
      }
    }
  }
}

// ---------------- 256x256 GEMM v4: 2 phases / K-tile, 1 vmcnt / K-tile ----------------
// LDS: 2 bufs x 8 units x [64 rows][64 k] bf16; key = row&7 (empirically 0-conflict).
// Units: U0..U3 = A rows 0-63/.../192-255; U4..U7 = B likewise.
// P0: read ALL B (both ks, held) + A ks0 (16 ds_reads), stage (k+1).A, 32 MFMA.
// P1: read A ks1 (8 ds_reads), stage (k+2).B, vmcnt(4) [tail 0], 32 MFMA.
// FIFO ledger (steady): at k.P1 outstanding = [k+1.B, k+1.A, k+2.B] = 12 -> vmcnt(4)
// drains ALL of tile k+1. Region safety: B stage lands >=1 barrier after P0's B reads
// (lgkm-drained); A stage targets opposite buffer.
// MODE 0: bf16(relu(acc+bias))   MODE 1: bf16(acc) -> out + z*M*N (split-K partial)
template <int MODE>
__launch_bounds__(512, 2)
__global__ void gemm8ph_kernel(const uint16_t* __restrict__ A, const uint16_t* __restrict__ Bt,
                               const float* __restrict__ bias, void* __restrict__ out,
                               int M, int N, int Klen, int lda, int ldb) {
  extern __shared__ uint16_t lds[];   // 2 x 32768 elems = 128 KB
  const int tid  = threadIdx.x;
  const int lane = tid & 63;
  const int wave = tid >> 6;

  const int nwg = gridDim.x * gridDim.y;
  int wg = blockIdx.y * gridDim.x + blockIdx.x;
  wg = (wg & 7) * (nwg >> 3) + (wg >> 3);
  const int bx = wg % gridDim.x, by = wg / gridDim.x;
  const int m0 = by * 256, n0 = bx * 256;

  const int z = blockIdx.z;
  A  += (size_t)z * Klen;
  Bt += (size_t)z * Klen;

  const int wm = (wave >> 2) * 128;
  const int wn = (wave & 3) * 64;

  f32x4 acc[8][4] = {};

  // ---- staging: thread t stages chunk t of each 8KB unit (row = t>>3, phys slot = t&7) ----
  const int srw = tid >> 3;            // 0..63
  const int sp  = tid & 7;
  const uint16_t* gu[8];
#pragma unroll
  for (int u = 0; u < 8; ++u) {
    const uint16_t* base = (u < 4) ? A + (size_t)(m0 + u * 64) * lda
                                   : Bt + (size_t)(n0 + (u - 4) * 64) * ldb;
    const int ld = (u < 4) ? lda : ldb;
    gu[u] = base + (size_t)srw * ld + ((sp ^ (srw & 7)) * 8);   // key: row&7
  }

  const int nk = Klen / 64;

#define STAGE8(T, U)                                                                          \
  if ((T) < nk) {                                                                             \
    __builtin_amdgcn_global_load_lds(                                                         \
        (const __attribute__((address_space(1))) uint32_t*)(gu[U] + (size_t)(T) * 64),        \
        (__attribute__((address_space(3))) uint32_t*)(lds + ((T) & 1) * 32768 + (U) * 4096 +  \
                                                      tid * 8),                               \
        16, 0, 0);                                                                            \
  }

  // ---- read offsets (elem, within a 32768-elem tile buffer); ks=1 via ^32 ----
  const int fr = lane & 15;
  const int hi = lane >> 4;
  int aoff[8];
#pragma unroll
  for (int m = 0; m < 8; ++m) {
    const int u = (wm >> 6) + (m >> 2);
    const int R = (m & 3) * 16 + fr;
    aoff[m] = u * 4096 + R * 64 + ((hi ^ (R & 7)) * 8);   // slot = cg ^ (row&7)
  }
  int boff[4];
#pragma unroll
  for (int n = 0; n < 4; ++n) {
    const int u = 4 + (wn >> 6);
    const int R = n * 16 + fr;
    boff[n] = u * 4096 + R * 64 + ((hi ^ (R & 7)) * 8);
  }

  // ---- prologue: tile0 all 8 units + tile1 B units; drain to tile0-resident ----
  STAGE8(0, 0); STAGE8(0, 1); STAGE8(0, 2); STAGE8(0, 3);
  STAGE8(0, 4); STAGE8(0, 5); STAGE8(0, 6); STAGE8(0, 7);
  STAGE8(1, 4); STAGE8(1, 5); STAGE8(1, 6); STAGE8(1, 7);
  asm volatile("s_waitcnt vmcnt(4)" ::: "memory");
  __builtin_amdgcn_s_barrier();

#define LD8(off) (*reinterpret_cast<const bf16x8*>(bufp + (off)))
#define PHASE_MFMA32(KS)                                                      \
  __builtin_amdgcn_s_setprio(1);                                              \
  _Pragma("unroll") for (int mm = 0; mm < 8; ++mm)                            \
    _Pragma("unroll") for (int n = 0; n < 4; ++n)                             \
      acc[mm][n] = __builtin_amdgcn_mfma_f32_16x16x32_bf16(                   \
          aq[mm], bq[n][KS], acc[mm][n], 0, 0, 0);                            \
  __builtin_amdgcn_s_setprio(0);

  for (int k = 0; k < nk; ++k) {
    const uint16_t* bufp = lds + (k & 1) * 32768;
    bf16x8 bq[4][2], aq[8];
    // ---- P0: all B (held) + A ks0; stage (k+1).A; 32 MFMA ----
#pragma unroll
    for (int n = 0; n < 4; ++n) { bq[n][0] = LD8(boff[n]); bq[n][1] = LD8(boff[n] ^ 32); }
#pragma unroll
    for (int mm = 0; mm < 8; ++mm) aq[mm] = LD8(aoff[mm]);
    STAGE8(k + 1, 0); STAGE8(k + 1, 1); STAGE8(k + 1, 2); STAGE8(k + 1, 3);
    __builtin_amdgcn_s_barrier();
    asm volatile("s_waitcnt lgkmcnt(0)" ::: "memory");
    __builtin_amdgcn_sched_barrier(0);
    PHASE_MFMA32(0);
    __builtin_amdgcn_s_barrier();
    // ---- P1: A ks1; stage (k+2).B; single vmcnt; 32 MFMA ----
#pragma unroll
    for (int mm = 0; mm < 8; ++mm) aq[mm] = LD8(aoff[mm] ^ 32);
    STAGE8(k + 2, 4); STAGE8(k + 2, 5); STAGE8(k + 2, 6); STAGE8(k + 2, 7);
    if (k < nk - 2) { asm volatile("s_waitcnt vmcnt(4)" ::: "memory"); }
    else            { asm volatile("s_waitcnt vmcnt(0)" ::: "memory"); }
    __builtin_amdgcn_s_barrier();
    asm volatile("s_waitcnt lgkmcnt(0)" ::: "memory");
    __builtin_amdgcn_sched_barrier(0);
    PHASE_MFMA32(1);
    __builtin_amdgcn_s_barrier();
  }
#undef PHASE_MFMA32
#undef LD8
#undef STAGE8

  // ---- epilogue: C/D layout col = lane&15, row = (lane>>4)*4 + reg ----
  const int cn  = lane & 15;
  const int cm4 = (lane >> 4) * 4;
  uint16_t* outp = (uint16_t*)out;
  if constexpr (MODE == 1) outp += (size_t)z * M * N;
  float bias_n[4];
  if constexpr (MODE == 0) {
#pragma unroll
    for (int n = 0; n < 4; ++n) bias_n[n] = bias[n0 + wn + n * 16 + cn];
  }
#pragma unroll
  for (int m = 0; m < 8; ++m) {
#pragma unroll
    for (int n = 0; n < 4; ++n) {
      const int gm = m0 + wm + m * 16 + cm4;
      const int gn = n0 + wn + n * 16 + cn;
#pragma unroll
      for (int r = 0; r < 4; ++r) {
        const size_t idx = (size_t)(gm + r) * N + gn;
        if constexpr (MODE == 0) {
          outp[idx] = f2bf(fmaxf(acc[m][n][r] + bias_n[n], 0.f));
        } else {
          outp[idx] = f2bf(acc[m][n][r]);
        }
      }
    }
  }
}

// ---------------- LN1: hb = bf16(LN(r1b)*g + b), r1b is bf16 ----------------
__global__ void ln1_kernel(const uint16_t* __restrict__ in,
                           const float* __restrict__ g,
                           const float* __restrict__ b,
                           uint16_t* __restrict__ outb) {
  const int row = blockIdx.x;
  const int t = threadIdx.x;
  const ushort4 r4 = reinterpret_cast<const ushort4*>(in + (size_t)row * 1024)[t];
  float4 v;
  v.x = bf2f(r4.x); v.y = bf2f(r4.y); v.z = bf2f(r4.z); v.w = bf2f(r4.w);
  float s  = v.x + v.y + v.z + v.w;
  float s2 = v.x * v.x + v.y * v.y + v.z * v.z + v.w * v.w;
#pragma unroll
  for (int o = 32; o > 0; o >>= 1) { s += __shfl_down(s, o); s2 += __shfl_down(s2, o); }
  __shared__ float red[8];
  const int lane = t & 63, wave = t >> 6;
  if (lane == 0) { red[wave] = s; red[4 + wave] = s2; }
  __syncthreads();
  const float S  = red[0] + red[1] + red[2] + red[3];
  const float S2 = red[4] + red[5] + red[6] + red[7];
  const float mu  = S * (1.f / 1024.f);
  const float var = S2 * (1.f / 1024.f) - mu * mu;
  const float rs  = rsqrtf(var + 1e-5f);
  const float4 gg = reinterpret_cast<const float4*>(g)[t];
  const float4 bb = reinterpret_cast<const float4*>(b)[t];
  ushort4 ob;
  ob.x = f2bf((v.x - mu) * rs * gg.x + bb.x);
  ob.y = f2bf((v.y - mu) * rs * gg.y + bb.y);
  ob.z = f2bf((v.z - mu) * rs * gg.z + bb.z);
  ob.w = f2bf((v.w - mu) * rs * gg.w + bb.w);
  reinterpret_cast<ushort4*>(outb + (size_t)row * 1024)[t] = ob;
}

// ---------------- LN2: out = LN(sum_z pp[z] + b2 + h)*g + be ----------------
__global__ void ln2_kernel(const uint16_t* __restrict__ pp, size_t pstride,
                           const uint16_t* __restrict__ hb, const float* __restrict__ b2,
                           const float* __restrict__ g, const float* __restrict__ be,
                           float* __restrict__ out) {
  const int row = blockIdx.x;
  const int t = threadIdx.x;
  const size_t base = (size_t)row * 1024;
  const ushort4 h4 = reinterpret_cast<const ushort4*>(hb + base)[t];
  const float4 c2 = reinterpret_cast<const float4*>(b2)[t];
  float4 v;
  v.x = c2.x + bf2f(h4.x); v.y = c2.y + bf2f(h4.y);
  v.z = c2.z + bf2f(h4.z); v.w = c2.w + bf2f(h4.w);
#pragma unroll
  for (int zz = 0; zz < 4; ++zz) {
    const ushort4 p4 = reinterpret_cast<const ushort4*>(pp + zz * pstride + base)[t];
    v.x += bf2f(p4.x); v.y += bf2f(p4.y); v.z += bf2f(p4.z); v.w += bf2f(p4.w);
  }
  float s  = v.x + v.y + v.z + v.w;
  float s2 = v.x * v.x + v.y * v.y + v.z * v.z + v.w * v.w;
#pragma unroll
  for (int o = 32; o > 0; o >>= 1) { s += __shfl_down(s, o); s2 += __shfl_down(s2, o); }
  __shared__ float red[8];
  const int lane = t & 63, wave = t >> 6;
  if (lane == 0) { red[wave] = s; red[4 + wave] = s2; }
  __syncthreads();
  const float S  = red[0] + red[1] + red[2] + red[3];
  const float S2 = red[4] + red[5] + red[6] + red[7];
  const float mu  = S * (1.f / 1024.f);
  const float var = S2 * (1.f / 1024.f) - mu * mu;
  const float rs  = rsqrtf(var + 1e-5f);
  const float4 gg = reinterpret_cast<const float4*>(g)[t];
  const float4 bb = reinterpret_cast<const float4*>(be)[t];
  float4 o;
  o.x = (v.x - mu) * rs * gg.x + bb.x;
  o.y = (v.y - mu) * rs * gg.y + bb.y;
  o.z = (v.z - mu) * rs * gg.z + bb.z;
  o.w = (v.w - mu) * rs * gg.w + bb.w;
  reinterpret_cast<float4*>(out + base)[t] = o;
}

// ---------------- launch ----------------
extern "C" void kernel_launch(void* const* d_in, const int* in_sizes, int n_in,
                              void* d_out, int out_size, void* d_ws, size_t ws_size,
                              hipStream_t stream) {
  // hollow attention == identity: out = attn@v = v, so the layer is
  // r1 = x + x@(Wv@Wo) + (bv@Wo+bo); h = LN1(r1); r2 = h + relu(h@W1+b1)@W2 + b2; out = LN2(r2)
  const float* x   = (const float*)d_in[0];
  const float* Wv  = (const float*)d_in[6];
  const float* bv  = (const float*)d_in[7];
  const float* Wo  = (const float*)d_in[8];
  const float* bo  = (const float*)d_in[9];
  const float* W1  = (const float*)d_in[10];
  const float* b1  = (const float*)d_in[11];
  const float* W2  = (const float*)d_in[12];
  const float* b2  = (const float*)d_in[13];
  const float* g1  = (const float*)d_in[14];
  const float* be1 = (const float*)d_in[15];
  const float* g2  = (const float*)d_in[16];
  const float* be2 = (const float*)d_in[17];
  float* out = (float*)d_out;

  constexpr int M = 4096, DM = 1024, FF = 4096;

  char* p = (char*)d_ws;
  auto alloc = [&](size_t bytes) {
    char* r = p;
    p += (bytes + 255) & ~(size_t)255;
    return r;
  };
  uint16_t* xb  = (uint16_t*)alloc((size_t)M * DM * 2);
  uint16_t* wvb = (uint16_t*)alloc((size_t)DM * DM * 2);
  uint16_t* woT = (uint16_t*)alloc((size_t)DM * DM * 2);
  uint16_t* w1t = (uint16_t*)alloc((size_t)FF * DM * 2);
  uint16_t* w2t = (uint16_t*)alloc((size_t)DM * FF * 2);
  uint16_t* wcT = (uint16_t*)alloc((size_t)DM * DM * 2);
  float*    bc  = (float*)   alloc((size_t)DM * 4);
  uint16_t* r1b = (uint16_t*)alloc((size_t)M * DM * 2);
  uint16_t* hb  = (uint16_t*)alloc((size_t)M * DM * 2);
  uint16_t* tb  = (uint16_t*)alloc((size_t)M * FF * 2);
  uint16_t* pp  = (uint16_t*)alloc((size_t)4 * M * DM * 2);  // split-K bf16 partials

  (void)hipFuncSetAttribute(reinterpret_cast<const void*>(gemm8ph_kernel<0>),
                            hipFuncAttributeMaxDynamicSharedMemorySize, 131072);
  (void)hipFuncSetAttribute(reinterpret_cast<const void*>(gemm8ph_kernel<1>),
                            hipFuncAttributeMaxDynamicSharedMemorySize, 131072);

  // fused preamble: cvt x, cvt Wv, Wo^T, W1^T, W2^T, bc  (one launch)
  prep_kernel<<<4096 + 1024 + 1024 + 4096 + 4096 + 32, 256, 0, stream>>>(
      x, Wv, Wo, W1, W2, bv, bo, xb, wvb, woT, w1t, w2t, bc);

  // WcT = (Wv@Wo)^T : C[j][i] = sum_k WoT[j][k] * Wv[i][k]
  gemm2ph_kernel<0><<<dim3(DM / BN, DM / BM), 256, 0, stream>>>(
      woT, wvb, nullptr, nullptr, wcT, DM, DM, DM, DM, DM);
  // r1b = bf16(x + x@Wc + bc)
  gemm2ph_kernel<1><<<dim3(DM / BN, M / BM), 256, 0, stream>>>(
      xb, wcT, bc, x, r1b, M, DM, DM, DM, DM);
  // h = LN1(r1b)
  ln1_kernel<<<M, 256, 0, stream>>>(r1b, g1, be1, hb);
  // t = relu(h@W1 + b1)   [v4]
  gemm8ph_kernel<0><<<dim3(FF / 256, M / 256), 512, 131072, stream>>>(
      hb, w1t, b1, tb, M, FF, DM, DM, DM);
  // pp[z] = t[:, z*1024:(z+1)*1024] @ W2[z*1024:(z+1)*1024, :]   [v4, split-K=4]
  gemm8ph_kernel<1><<<dim3(DM / 256, M / 256, 4), 512, 131072, stream>>>(
      tb, w2t, nullptr, pp, M, DM, FF / 4, FF, FF);
  // out = LN2(h + sum_z pp[z] + b2)
  ln2_kernel<<<M, 256, 0, stream>>>(pp, (size_t)M * DM, hb, b2, g2, be2, out);
}

// Round 7
// 143.154 us; speedup vs baseline: 1.4948x; 1.0150x over previous
//
#include <hip/hip_runtime.h>
#include <stdint.h>

typedef __bf16 bf16x8 __attribute__((ext_vector_type(8)));
typedef float f32x4 __attribute__((ext_vector_type(4)));

__device__ __forceinline__ uint16_t f2bf(float f) {
  union { float f; uint32_t u; } c; c.f = f;
  uint32_t u = c.u;
  u += 0x7fffu + ((u >> 16) & 1u);   // round-to-nearest-even
  return (uint16_t)(u >> 16);
}
__device__ __forceinline__ float bf2f(uint16_t u) {
  union { uint32_t u; float f; } c; c.u = (uint32_t)u << 16; return c.f;
}

// ---------------- fused preamble: cvt x, cvt Wv, 3 transposes, bc ----------------
__device__ __forceinline__ void cvt_body(const float* __restrict__ in,
                                         uint16_t* __restrict__ out, int i) {
  float4 v = reinterpret_cast<const float4*>(in)[i];
  ushort4 o;
  o.x = f2bf(v.x); o.y = f2bf(v.y); o.z = f2bf(v.z); o.w = f2bf(v.w);
  reinterpret_cast<ushort4*>(out)[i] = o;
}

__global__ void prep_kernel(const float* __restrict__ x, const float* __restrict__ Wv,
                            const float* __restrict__ Wo, const float* __restrict__ W1,
                            const float* __restrict__ W2, const float* __restrict__ bv,
                            const float* __restrict__ bo,
                            uint16_t* __restrict__ xb, uint16_t* __restrict__ wvb,
                            uint16_t* __restrict__ woT, uint16_t* __restrict__ w1t,
                            uint16_t* __restrict__ w2t, float* __restrict__ bc) {
  __shared__ float tsh[32][33];
  __shared__ float red[8][32];
  int b = blockIdx.x;
  const int t = threadIdx.x;
  if (b < 4096) { cvt_body(x, xb, b * 256 + t); return; }
  b -= 4096;
  if (b < 1024) { cvt_body(Wv, wvb, b * 256 + t); return; }
  b -= 1024;

  const float* tin = nullptr; uint16_t* tout = nullptr;
  int R = 0, C = 0, bx = 0, by = 0;
  if (b < 1024) {                      // Wo^T: 1024x1024
    tin = Wo; tout = woT; R = 1024; C = 1024; bx = b & 31; by = b >> 5;
  } else if (b < 1024 + 4096) {        // W1^T: [1024,4096] -> [4096,1024]
    const int bb = b - 1024;
    tin = W1; tout = w1t; R = 1024; C = 4096; bx = bb & 127; by = bb >> 7;
  } else if (b < 1024 + 8192) {        // W2^T: [4096,1024] -> [1024,4096]
    const int bb = b - (1024 + 4096);
    tin = W2; tout = w2t; R = 4096; C = 1024; bx = bb & 31; by = bb >> 5;
  } else {                             // bc = bv @ Wo + bo : 32 blocks
    const int jb = b - (1024 + 8192);
    const int jl = t & 31, kg = t >> 5;
    const int j = jb * 32 + jl;
    float s = 0.f;
    const int k0 = kg * 128;
    for (int k = k0; k < k0 + 128; ++k) s += bv[k] * Wo[(size_t)k * 1024 + j];
    red[kg][jl] = s;
    __syncthreads();
    if (kg == 0) {
      float acc = bo[j];
#pragma unroll
      for (int q = 0; q < 8; ++q) acc += red[q][jl];
      bc[j] = acc;
    }
    return;
  }
  const int tx = t & 31, ty = t >> 5;
  const int c0 = bx * 32, r0 = by * 32;
#pragma unroll
  for (int i = 0; i < 4; ++i)
    tsh[ty + i * 8][tx] = tin[(size_t)(r0 + ty + i * 8) * C + (c0 + tx)];
  __syncthreads();
#pragma unroll
  for (int i = 0; i < 4; ++i)
    tout[(size_t)(c0 + ty + i * 8) * R + (r0 + tx)] = f2bf(tsh[tx][ty + i * 8]);
}

// ---------------- 2-phase 128x128 GEMM (small GEMMs; measured 0 bank conflicts) ----------------
// MODE 0: bf16(acc + bias?)   MODE 1: bf16(acc + bias + res_f32)
constexpr int BM = 128, BN = 128, BK = 64;

template <int MODE>
__launch_bounds__(256, 2)
__global__ void gemm2ph_kernel(const uint16_t* __restrict__ A, const uint16_t* __restrict__ Bt,
                               const float* __restrict__ bias, const float* __restrict__ res,
                               void* __restrict__ out, int M, int N, int Klen, int lda, int ldb) {
  __shared__ uint16_t sAB[2][2][BM * BK];
  const int tid  = threadIdx.x;
  const int lane = tid & 63;
  const int wave = tid >> 6;

  const int nwg = gridDim.x * gridDim.y;
  int wg = blockIdx.y * gridDim.x + blockIdx.x;
  wg = (wg & 7) * (nwg >> 3) + (wg >> 3);
  const int bx = wg % gridDim.x, by = wg / gridDim.x;
  const int m0 = by * BM, n0 = bx * BN;

  const int wm = (wave >> 1) * 64;
  const int wn = (wave & 1) * 64;

  f32x4 acc[4][4] = {};

  const int srow = tid >> 3;
  const int scol = ((tid & 7) ^ (srow & 7)) * 8;
  const uint16_t* ga[4];
  const uint16_t* gb[4];
  uint32_t loff[4];
#pragma unroll
  for (int g = 0; g < 4; ++g) {
    const int row = srow + 32 * g;
    ga[g] = A + (size_t)(m0 + row) * lda + scol;
    gb[g] = Bt + (size_t)(n0 + row) * ldb + scol;
    loff[g] = (uint32_t)(tid + g * 256) * 8;
  }

  const int fr = lane & 15;
  const int hi = lane >> 4;
  const int rx = fr & 7;

  const int nk = Klen / BK;

#define STAGE2(buf, kt)                                                                   \
  {                                                                                       \
    _Pragma("unroll")                                                                     \
    for (int g = 0; g < 4; ++g) {                                                         \
      __builtin_amdgcn_global_load_lds(                                                   \
          (const __attribute__((address_space(1))) uint32_t*)(ga[g] + (size_t)(kt) * BK), \
          (__attribute__((address_space(3))) uint32_t*)(&sAB[buf][0][loff[g]]), 16, 0, 0);\
      __builtin_amdgcn_global_load_lds(                                                   \
          (const __attribute__((address_space(1))) uint32_t*)(gb[g] + (size_t)(kt) * BK), \
          (__attribute__((address_space(3))) uint32_t*)(&sAB[buf][1][loff[g]]), 16, 0, 0);\
    }                                                                                     \
  }

  STAGE2(0, 0);
  __syncthreads();

  int cur = 0;
  for (int kt = 0; kt < nk; ++kt) {
    if (kt + 1 < nk) STAGE2(cur ^ 1, kt + 1);
    const uint16_t* pA = &sAB[cur][0][0];
    const uint16_t* pB = &sAB[cur][1][0];
    bf16x8 af[4][2], bb[4][2];
#pragma unroll
    for (int m = 0; m < 4; ++m)
#pragma unroll
      for (int ks = 0; ks < 2; ++ks) {
        const int slot = (ks * 4 + hi) ^ rx;
        af[m][ks] = *reinterpret_cast<const bf16x8*>(pA + (wm + m * 16 + fr) * BK + slot * 8);
        bb[m][ks] = *reinterpret_cast<const bf16x8*>(pB + (wn + m * 16 + fr) * BK + slot * 8);
      }
#pragma unroll
    for (int ks = 0; ks < 2; ++ks)
#pragma unroll
      for (int m = 0; m < 4; ++m)
#pragma unroll
        for (int n = 0; n < 4; ++n)
          acc[m][n] = __builtin_amdgcn_mfma_f32_16x16x32_bf16(af[m][ks], bb[n][ks], acc[m][n], 0, 0, 0);
    __syncthreads();
    cur ^= 1;
  }
#undef STAGE2

  const int cn  = lane & 15;
  const int cm4 = (lane >> 4) * 4;
#pragma unroll
  for (int m = 0; m < 4; ++m) {
#pragma unroll
    for (int n = 0; n < 4; ++n) {
      const int gm = m0 + wm + m * 16 + cm4;
      const int gn = n0 + wn + n * 16 + cn;
      const float bbv = bias ? bias[gn] : 0.f;
#pragma unroll
      for (int r = 0; r < 4; ++r) {
        const size_t idx = (size_t)(gm + r) * N + gn;
        const float vv = acc[m][n][r] + bbv;
        if constexpr (MODE == 0) {
          ((uint16_t*)out)[idx] = f2bf(vv);
        } else {
          ((uint16_t*)out)[idx] = f2bf(vv + res[idx]);
        }
      }
    }
  }
}

// ---------------- 256x256 GEMM v5: 2 barriers / K-tile, compiler fine-grained lgkm ----------------
// LDS: 2 bufs x 8 units x [64 rows][64 k] bf16; key = row&7 (measured 0-conflict).
// Units: U0..U3 = A rows 0-63/.../192-255; U4..U7 = B likewise.
// P0: plain-load reads bq(both ks)+aq ks0 (16 ds_reads), stage (k+1).A -> OPPOSITE buf
//     (never a hazard), MFMA32 ks0 (compiler inserts fine lgkmcnt per use),
//     free lgkmcnt(0) (all reads already consumed; pins reads before barrier), barrier.
// P1: reads aq ks1 (8), stage (k+2).B -> same-buf B regions (safe: all waves' bq reads
//     consumed before the P0 barrier), MFMA32 ks1, vmcnt(4) [tail 0], lgkm pin, barrier.
// FIFO ledger (steady): at k.P1 vmcnt: outstanding = [B(k+1) 4, A(k+1) 4, B(k+2) 4] = 12
//   -> vmcnt(4) drains tile k+1 exactly. Prologue {0.A,0.B,1.B}, vmcnt(4) -> tile0 resident.
//   Tail: k >= nk-2 -> vmcnt(0).
// MODE 0: bf16(relu(acc+bias))   MODE 1: bf16(acc) -> out + z*M*N (split-K partial)
template <int MODE>
__launch_bounds__(512, 2)
__global__ void gemm8ph_kernel(const uint16_t* __restrict__ A, const uint16_t* __restrict__ Bt,
                               const float* __restrict__ bias, void* __restrict__ out,
                               int M, int N, int Klen, int lda, int ldb) {
  extern __shared__ uint16_t lds[];   // 2 x 32768 elems = 128 KB
  const int tid  = threadIdx.x;
  const int lane = tid & 63;
  const int wave = tid >> 6;

  const int nwg = gridDim.x * gridDim.y;
  int wg = blockIdx.y * gridDim.x + blockIdx.x;
  wg = (wg & 7) * (nwg >> 3) + (wg >> 3);
  const int bx = wg % gridDim.x, by = wg / gridDim.x;
  const int m0 = by * 256, n0 = bx * 256;

  const int z = blockIdx.z;
  A  += (size_t)z * Klen;
  Bt += (size_t)z * Klen;

  const int wm = (wave >> 2) * 128;
  const int wn = (wave & 3) * 64;

  f32x4 acc[8][4] = {};

  // ---- staging: thread t stages chunk t of each 8KB unit (row = t>>3, phys slot = t&7) ----
  const int srw = tid >> 3;            // 0..63
  const int sp  = tid & 7;
  const uint16_t* gu[8];
#pragma unroll
  for (int u = 0; u < 8; ++u) {
    const uint16_t* base = (u < 4) ? A + (size_t)(m0 + u * 64) * lda
                                   : Bt + (size_t)(n0 + (u - 4) * 64) * ldb;
    const int ld = (u < 4) ? lda : ldb;
    gu[u] = base + (size_t)srw * ld + ((sp ^ (srw & 7)) * 8);   // key: row&7
  }

  const int nk = Klen / 64;

#define STAGE8(T, U)                                                                          \
  if ((T) < nk) {                                                                             \
    __builtin_amdgcn_global_load_lds(                                                         \
        (const __attribute__((address_space(1))) uint32_t*)(gu[U] + (size_t)(T) * 64),        \
        (__attribute__((address_space(3))) uint32_t*)(lds + ((T) & 1) * 32768 + (U) * 4096 +  \
                                                      tid * 8),                               \
        16, 0, 0);                                                                            \
  }

  // ---- read offsets (elem, within a 32768-elem tile buffer); ks=1 via ^32 ----
  const int fr = lane & 15;
  const int hi = lane >> 4;
  int aoff[8];
#pragma unroll
  for (int m = 0; m < 8; ++m) {
    const int u = (wm >> 6) + (m >> 2);
    const int R = (m & 3) * 16 + fr;
    aoff[m] = u * 4096 + R * 64 + ((hi ^ (R & 7)) * 8);   // slot = cg ^ (row&7)
  }
  int boff[4];
#pragma unroll
  for (int n = 0; n < 4; ++n) {
    const int u = 4 + (wn >> 6);
    const int R = n * 16 + fr;
    boff[n] = u * 4096 + R * 64 + ((hi ^ (R & 7)) * 8);
  }

  // ---- prologue: tile0 (A+B) + tile1.B; vmcnt(4) drains tile0 exactly ----
  STAGE8(0, 0); STAGE8(0, 1); STAGE8(0, 2); STAGE8(0, 3);
  STAGE8(0, 4); STAGE8(0, 5); STAGE8(0, 6); STAGE8(0, 7);
  STAGE8(1, 4); STAGE8(1, 5); STAGE8(1, 6); STAGE8(1, 7);
  asm volatile("s_waitcnt vmcnt(4)" ::: "memory");
  __builtin_amdgcn_s_barrier();

#define LD8(off) (*reinterpret_cast<const bf16x8*>(bufp + (off)))
#define PHASE_MFMA32(KS)                                                      \
  __builtin_amdgcn_s_setprio(1);                                              \
  _Pragma("unroll") for (int mm = 0; mm < 8; ++mm)                            \
    _Pragma("unroll") for (int n = 0; n < 4; ++n)                             \
      acc[mm][n] = __builtin_amdgcn_mfma_f32_16x16x32_bf16(                   \
          aq[mm], bq[n][KS], acc[mm][n], 0, 0, 0);                            \
  __builtin_amdgcn_s_setprio(0);

  for (int k = 0; k < nk; ++k) {
    const uint16_t* bufp = lds + (k & 1) * 32768;
    bf16x8 bq[4][2], aq[8];
    // ---- P0 ----
#pragma unroll
    for (int n = 0; n < 4; ++n) { bq[n][0] = LD8(boff[n]); bq[n][1] = LD8(boff[n] ^ 32); }
#pragma unroll
    for (int mm = 0; mm < 8; ++mm) aq[mm] = LD8(aoff[mm]);
    STAGE8(k + 1, 0); STAGE8(k + 1, 1); STAGE8(k + 1, 2); STAGE8(k + 1, 3);
    PHASE_MFMA32(0);
    asm volatile("s_waitcnt lgkmcnt(0)" ::: "memory");  // free (reads consumed); pins order
    __builtin_amdgcn_s_barrier();
    // ---- P1 ----
#pragma unroll
    for (int mm = 0; mm < 8; ++mm) aq[mm] = LD8(aoff[mm] ^ 32);
    STAGE8(k + 2, 4); STAGE8(k + 2, 5); STAGE8(k + 2, 6); STAGE8(k + 2, 7);
    PHASE_MFMA32(1);
    if (k < nk - 2) { asm volatile("s_waitcnt vmcnt(4)" ::: "memory"); }
    else            { asm volatile("s_waitcnt vmcnt(0)" ::: "memory"); }
    asm volatile("s_waitcnt lgkmcnt(0)" ::: "memory");
    __builtin_amdgcn_s_barrier();
  }
#undef PHASE_MFMA32
#undef LD8
#undef STAGE8

  // ---- epilogue: C/D layout col = lane&15, row = (lane>>4)*4 + reg ----
  const int cn  = lane & 15;
  const int cm4 = (lane >> 4) * 4;
  uint16_t* outp = (uint16_t*)out;
  if constexpr (MODE == 1) outp += (size_t)z * M * N;
  float bias_n[4];
  if constexpr (MODE == 0) {
#pragma unroll
    for (int n = 0; n < 4; ++n) bias_n[n] = bias[n0 + wn + n * 16 + cn];
  }
#pragma unroll
  for (int m = 0; m < 8; ++m) {
#pragma unroll
    for (int n = 0; n < 4; ++n) {
      const int gm = m0 + wm + m * 16 + cm4;
      const int gn = n0 + wn + n * 16 + cn;
#pragma unroll
      for (int r = 0; r < 4; ++r) {
        const size_t idx = (size_t)(gm + r) * N + gn;
        if constexpr (MODE == 0) {
          outp[idx] = f2bf(fmaxf(acc[m][n][r] + bias_n[n], 0.f));
        } else {
          outp[idx] = f2bf(acc[m][n][r]);
        }
      }
    }
  }
}

// ---------------- LN1: hb = bf16(LN(r1b)*g + b), r1b is bf16 ----------------
__global__ void ln1_kernel(const uint16_t* __restrict__ in,
                           const float* __restrict__ g,
                           const float* __restrict__ b,
                           uint16_t* __restrict__ outb) {
  const int row = blockIdx.x;
  const int t = threadIdx.x;
  const ushort4 r4 = reinterpret_cast<const ushort4*>(in + (size_t)row * 1024)[t];
  float4 v;
  v.x = bf2f(r4.x); v.y = bf2f(r4.y); v.z = bf2f(r4.z); v.w = bf2f(r4.w);
  float s  = v.x + v.y + v.z + v.w;
  float s2 = v.x * v.x + v.y * v.y + v.z * v.z + v.w * v.w;
#pragma unroll
  for (int o = 32; o > 0; o >>= 1) { s += __shfl_down(s, o); s2 += __shfl_down(s2, o); }
  __shared__ float red[8];
  const int lane = t & 63, wave = t >> 6;
  if (lane == 0) { red[wave] = s; red[4 + wave] = s2; }
  __syncthreads();
  const float S  = red[0] + red[1] + red[2] + red[3];
  const float S2 = red[4] + red[5] + red[6] + red[7];
  const float mu  = S * (1.f / 1024.f);
  const float var = S2 * (1.f / 1024.f) - mu * mu;
  const float rs  = rsqrtf(var + 1e-5f);
  const float4 gg = reinterpret_cast<const float4*>(g)[t];
  const float4 bb = reinterpret_cast<const float4*>(b)[t];
  ushort4 ob;
  ob.x = f2bf((v.x - mu) * rs * gg.x + bb.x);
  ob.y = f2bf((v.y - mu) * rs * gg.y + bb.y);
  ob.z = f2bf((v.z - mu) * rs * gg.z + bb.z);
  ob.w = f2bf((v.w - mu) * rs * gg.w + bb.w);
  reinterpret_cast<ushort4*>(outb + (size_t)row * 1024)[t] = ob;
}

// ---------------- LN2: out = LN(sum_z pp[z] + b2 + h)*g + be ----------------
__global__ void ln2_kernel(const uint16_t* __restrict__ pp, size_t pstride,
                           const uint16_t* __restrict__ hb, const float* __restrict__ b2,
                           const float* __restrict__ g, const float* __restrict__ be,
                           float* __restrict__ out) {
  const int row = blockIdx.x;
  const int t = threadIdx.x;
  const size_t base = (size_t)row * 1024;
  const ushort4 h4 = reinterpret_cast<const ushort4*>(hb + base)[t];
  const float4 c2 = reinterpret_cast<const float4*>(b2)[t];
  float4 v;
  v.x = c2.x + bf2f(h4.x); v.y = c2.y + bf2f(h4.y);
  v.z = c2.z + bf2f(h4.z); v.w = c2.w + bf2f(h4.w);
#pragma unroll
  for (int zz = 0; zz < 4; ++zz) {
    const ushort4 p4 = reinterpret_cast<const ushort4*>(pp + zz * pstride + base)[t];
    v.x += bf2f(p4.x); v.y += bf2f(p4.y); v.z += bf2f(p4.z); v.w += bf2f(p4.w);
  }
  float s  = v.x + v.y + v.z + v.w;
  float s2 = v.x * v.x + v.y * v.y + v.z * v.z + v.w * v.w;
#pragma unroll
  for (int o = 32; o > 0; o >>= 1) { s += __shfl_down(s, o); s2 += __shfl_down(s2, o); }
  __shared__ float red[8];
  const int lane = t & 63, wave = t >> 6;
  if (lane == 0) { red[wave] = s; red[4 + wave] = s2; }
  __syncthreads();
  const float S  = red[0] + red[1] + red[2] + red[3];
  const float S2 = red[4] + red[5] + red[6] + red[7];
  const float mu  = S * (1.f / 1024.f);
  const float var = S2 * (1.f / 1024.f) - mu * mu;
  const float rs  = rsqrtf(var + 1e-5f);
  const float4 gg = reinterpret_cast<const float4*>(g)[t];
  const float4 bb = reinterpret_cast<const float4*>(be)[t];
  float4 o;
  o.x = (v.x - mu) * rs * gg.x + bb.x;
  o.y = (v.y - mu) * rs * gg.y + bb.y;
  o.z = (v.z - mu) * rs * gg.z + bb.z;
  o.w = (v.w - mu) * rs * gg.w + bb.w;
  reinterpret_cast<float4*>(out + base)[t] = o;
}

// ---------------- launch ----------------
extern "C" void kernel_launch(void* const* d_in, const int* in_sizes, int n_in,
                              void* d_out, int out_size, void* d_ws, size_t ws_size,
                              hipStream_t stream) {
  // hollow attention == identity: out = attn@v = v, so the layer is
  // r1 = x + x@(Wv@Wo) + (bv@Wo+bo); h = LN1(r1); r2 = h + relu(h@W1+b1)@W2 + b2; out = LN2(r2)
  const float* x   = (const float*)d_in[0];
  const float* Wv  = (const float*)d_in[6];
  const float* bv  = (const float*)d_in[7];
  const float* Wo  = (const float*)d_in[8];
  const float* bo  = (const float*)d_in[9];
  const float* W1  = (const float*)d_in[10];
  const float* b1  = (const float*)d_in[11];
  const float* W2  = (const float*)d_in[12];
  const float* b2  = (const float*)d_in[13];
  const float* g1  = (const float*)d_in[14];
  const float* be1 = (const float*)d_in[15];
  const float* g2  = (const float*)d_in[16];
  const float* be2 = (const float*)d_in[17];
  float* out = (float*)d_out;

  constexpr int M = 4096, DM = 1024, FF = 4096;

  char* p = (char*)d_ws;
  auto alloc = [&](size_t bytes) {
    char* r = p;
    p += (bytes + 255) & ~(size_t)255;
    return r;
  };
  uint16_t* xb  = (uint16_t*)alloc((size_t)M * DM * 2);
  uint16_t* wvb = (uint16_t*)alloc((size_t)DM * DM * 2);
  uint16_t* woT = (uint16_t*)alloc((size_t)DM * DM * 2);
  uint16_t* w1t = (uint16_t*)alloc((size_t)FF * DM * 2);
  uint16_t* w2t = (uint16_t*)alloc((size_t)DM * FF * 2);
  uint16_t* wcT = (uint16_t*)alloc((size_t)DM * DM * 2);
  float*    bc  = (float*)   alloc((size_t)DM * 4);
  uint16_t* r1b = (uint16_t*)alloc((size_t)M * DM * 2);
  uint16_t* hb  = (uint16_t*)alloc((size_t)M * DM * 2);
  uint16_t* tb  = (uint16_t*)alloc((size_t)M * FF * 2);
  uint16_t* pp  = (uint16_t*)alloc((size_t)4 * M * DM * 2);  // split-K bf16 partials

  (void)hipFuncSetAttribute(reinterpret_cast<const void*>(gemm8ph_kernel<0>),
                            hipFuncAttributeMaxDynamicSharedMemorySize, 131072);
  (void)hipFuncSetAttribute(reinterpret_cast<const void*>(gemm8ph_kernel<1>),
                            hipFuncAttributeMaxDynamicSharedMemorySize, 131072);

  // fused preamble: cvt x, cvt Wv, Wo^T, W1^T, W2^T, bc  (one launch)
  prep_kernel<<<4096 + 1024 + 1024 + 4096 + 4096 + 32, 256, 0, stream>>>(
      x, Wv, Wo, W1, W2, bv, bo, xb, wvb, woT, w1t, w2t, bc);

  // WcT = (Wv@Wo)^T : C[j][i] = sum_k WoT[j][k] * Wv[i][k]
  gemm2ph_kernel<0><<<dim3(DM / BN, DM / BM), 256, 0, stream>>>(
      woT, wvb, nullptr, nullptr, wcT, DM, DM, DM, DM, DM);
  // r1b = bf16(x + x@Wc + bc)
  gemm2ph_kernel<1><<<dim3(DM / BN, M / BM), 256, 0, stream>>>(
      xb, wcT, bc, x, r1b, M, DM, DM, DM, DM);
  // h = LN1(r1b)
  ln1_kernel<<<M, 256, 0, stream>>>(r1b, g1, be1, hb);
  // t = relu(h@W1 + b1)   [v5]
  gemm8ph_kernel<0><<<dim3(FF / 256, M / 256), 512, 131072, stream>>>(
      hb, w1t, b1, tb, M, FF, DM, DM, DM);
  // pp[z] = t[:, z*1024:(z+1)*1024] @ W2[z*1024:(z+1)*1024, :]   [v5, split-K=4]
  gemm8ph_kernel<1><<<dim3(DM / 256, M / 256, 4), 512, 131072, stream>>>(
      tb, w2t, nullptr, pp, M, DM, FF / 4, FF, FF);
  // out = LN2(h + sum_z pp[z] + b2)
  ln2_kernel<<<M, 256, 0, stream>>>(pp, (size_t)M * DM, hb, b2, g2, be2, out);
}